// Round 6
// baseline (1127.710 us; speedup 1.0000x reference)
//
#include <hip/hip_runtime.h>
#include <hip/hip_bf16.h>
#include <math.h>

// Problem constants (MambaEncoder)
#define Bz     8
#define Lz     8192
#define DM     128      // d_model
#define DI     256      // d_inner
#define DS     16       // d_state
#define DTR    8        // dt_rank
#define NDBL   40       // DTR + 2*DS
#define DEPTHN 4
#define BLz    (Bz*Lz)  // 65536 tokens
#define CHT    32       // scan chunk length == fused-GEMM M-tile
#define NCH    (Lz/CHT) // 256 chunks per sequence

typedef unsigned short bf16_t;
typedef __attribute__((ext_vector_type(8))) __bf16 bf8;
typedef __attribute__((ext_vector_type(4))) float f4;
typedef __attribute__((ext_vector_type(8))) unsigned short us8;

__device__ __forceinline__ float bf2f(bf16_t u) {
    return __uint_as_float(((unsigned)u) << 16);
}
__device__ __forceinline__ bf16_t f2bf(float f) {
    unsigned u = __float_as_uint(f);
    u = u + 0x7FFFu + ((u >> 16) & 1u);   // round-to-nearest-even
    return (bf16_t)(u >> 16);
}
__device__ __forceinline__ float fast_rcp(float x) {
    return __builtin_amdgcn_rcpf(x);
}

// ---------------------------------------------------------------------------
__global__ void k_zero_hg(float* __restrict__ hg) {
    int i = blockIdx.x * 256 + threadIdx.x;
    if (i < Bz * DM) hg[i] = 0.f;
}

// ---------------------------------------------------------------------------
// Convert weights fp32 -> bf16 (xproj padded from 40 to 64 rows with zeros).
// ---------------------------------------------------------------------------
__global__ __launch_bounds__(256) void k_wconv(const float* __restrict__ inw,
                                               const float* __restrict__ ow,
                                               const float* __restrict__ xw,
                                               bf16_t* __restrict__ inwb,
                                               bf16_t* __restrict__ owb,
                                               bf16_t* __restrict__ xwb) {
    int i = blockIdx.x * 256 + threadIdx.x;
    if (i < DEPTHN * 512 * DM) inwb[i] = f2bf(inw[i]);
    if (i < DEPTHN * DM * DI)  owb[i]  = f2bf(ow[i]);
    if (i < DEPTHN * 64 * DI) {
        int layer = i >> 14, rk = i & 16383, r = rk >> 8, k = rk & 255;
        xwb[i] = (r < NDBL) ? f2bf(xw[((size_t)layer * NDBL + r) * DI + k]) : (bf16_t)0;
    }
}

// ---------------------------------------------------------------------------
__global__ __launch_bounds__(256) void k_inproj(const float* __restrict__ x,
                                                const float* __restrict__ pw,
                                                const float* __restrict__ pb,
                                                float* __restrict__ h) {
    int t = blockIdx.x * 2 + (threadIdx.x >> 7);
    int d = threadIdx.x & 127;
    int b = t >> 13, l = t & (Lz - 1);
    float acc = pb[d];
#pragma unroll
    for (int c = 0; c < 3; ++c)
        acc += x[(size_t)(b * 3 + c) * Lz + l] * pw[d * 3 + c];
    h[(size_t)t * DM + d] = acc;
}

// ---------------------------------------------------------------------------
__global__ __launch_bounds__(256) void k_ln(const float* __restrict__ h,
                                            const float* __restrict__ w,
                                            const float* __restrict__ bias,
                                            bf16_t* __restrict__ xn) {
    int t    = blockIdx.x * 16 + (threadIdx.x >> 4);
    int lane = threadIdx.x & 15;
    const float4* hp = (const float4*)(h + (size_t)t * DM + lane * 8);
    float4 v0 = hp[0], v1 = hp[1];
    float s = v0.x + v0.y + v0.z + v0.w + v1.x + v1.y + v1.z + v1.w;
    float q = v0.x*v0.x + v0.y*v0.y + v0.z*v0.z + v0.w*v0.w +
              v1.x*v1.x + v1.y*v1.y + v1.z*v1.z + v1.w*v1.w;
#pragma unroll
    for (int off = 1; off < 16; off <<= 1) {
        s += __shfl_xor(s, off);
        q += __shfl_xor(q, off);
    }
    float mean = s * (1.f / DM);
    float var  = q * (1.f / DM) - mean * mean;
    float rstd = rsqrtf(var + 1e-5f);
    const float4* wp = (const float4*)(w + lane * 8);
    const float4* bp = (const float4*)(bias + lane * 8);
    float4 w0 = wp[0], w1 = wp[1], b0 = bp[0], b1 = bp[1];
    ushort4 o0, o1;
    o0.x = f2bf((v0.x - mean) * rstd * w0.x + b0.x);
    o0.y = f2bf((v0.y - mean) * rstd * w0.y + b0.y);
    o0.z = f2bf((v0.z - mean) * rstd * w0.z + b0.z);
    o0.w = f2bf((v0.w - mean) * rstd * w0.w + b0.w);
    o1.x = f2bf((v1.x - mean) * rstd * w1.x + b1.x);
    o1.y = f2bf((v1.y - mean) * rstd * w1.y + b1.y);
    o1.z = f2bf((v1.z - mean) * rstd * w1.z + b1.z);
    o1.w = f2bf((v1.w - mean) * rstd * w1.w + b1.w);
    ushort4* op = (ushort4*)(xn + (size_t)t * DM + lane * 8);
    op[0] = o0; op[1] = o1;
}

// ---------------------------------------------------------------------------
// MFMA GEMM 1: [M x 512] = xn[M x 128] @ in_w^T. Block: 64(M) x 256(N).
// ---------------------------------------------------------------------------
#define PADI 264
__global__ __launch_bounds__(256) void k_mfma_in(const bf16_t* __restrict__ A,
                                                 const bf16_t* __restrict__ Wb,
                                                 bf16_t* __restrict__ u_pre,
                                                 bf16_t* __restrict__ z) {
    __shared__ bf16_t tile[64 * PADI];
    int wave = threadIdx.x >> 6, lane = threadIdx.x & 63;
    int lr = lane & 15, lq = lane >> 4;
    int mBase = blockIdx.x * 64;
    int nBase = blockIdx.y * 256;
    int wm = (wave & 1) * 32, wn = (wave >> 1) * 128;
    f4 zf = {0.f, 0.f, 0.f, 0.f};
    f4 acc[2][8];
#pragma unroll
    for (int mi = 0; mi < 2; ++mi)
#pragma unroll
        for (int ni = 0; ni < 8; ++ni) acc[mi][ni] = zf;
    const bf16_t* Ap = A + (size_t)(mBase + wm + lr) * DM + lq * 8;
    const bf16_t* Bp = Wb + (size_t)(nBase + wn + lr) * DM + lq * 8;
#pragma unroll
    for (int kk = 0; kk < DM; kk += 32) {
        bf8 af[2], bq[8];
        af[0] = *(const bf8*)(Ap + kk);
        af[1] = *(const bf8*)(Ap + 16 * DM + kk);
#pragma unroll
        for (int ni = 0; ni < 8; ++ni)
            bq[ni] = *(const bf8*)(Bp + (size_t)ni * 16 * DM + kk);
#pragma unroll
        for (int mi = 0; mi < 2; ++mi)
#pragma unroll
            for (int ni = 0; ni < 8; ++ni)
                acc[mi][ni] = __builtin_amdgcn_mfma_f32_16x16x32_bf16(
                    af[mi], bq[ni], acc[mi][ni], 0, 0, 0);
    }
#pragma unroll
    for (int mi = 0; mi < 2; ++mi)
#pragma unroll
        for (int ni = 0; ni < 8; ++ni)
#pragma unroll
            for (int r = 0; r < 4; ++r)
                tile[(wm + mi * 16 + lq * 4 + r) * PADI + wn + ni * 16 + lr] =
                    f2bf(acc[mi][ni][r]);
    __syncthreads();
    bf16_t* dst = (blockIdx.y == 0) ? u_pre : z;
    for (int i = threadIdx.x; i < 2048; i += 256) {
        int row = i >> 5, col = (i & 31) * 8;
        us8 v = *(const us8*)&tile[row * PADI + col];
        *(us8*)&dst[(size_t)(mBase + row) * DI + col] = v;
    }
}

// ---------------------------------------------------------------------------
// dA power tree: dA[s] = e1^(s+1), depth 4 instead of 16-deep serial chain.
// ---------------------------------------------------------------------------
__device__ __forceinline__ void pow_tree(float e1, float dA[DS]) {
    float e2 = e1 * e1, e3 = e2 * e1, e4 = e2 * e2;
    float e8 = e4 * e4;
    dA[0] = e1;       dA[1] = e2;       dA[2] = e3;       dA[3] = e4;
    dA[4] = e4 * e1;  dA[5] = e4 * e2;  dA[6] = e4 * e3;  dA[7] = e8;
    dA[8] = e8 * e1;  dA[9] = e8 * e2;  dA[10] = e8 * e3; dA[11] = e8 * e4;
    dA[12] = e8 * dA[4]; dA[13] = e8 * dA[5]; dA[14] = e8 * dA[6];
    dA[15] = e8 * e8;
}

// ---------------------------------------------------------------------------
// FUSED: conv+SiLU staging -> xproj GEMM (dbl) -> scan1 (Q, sdt). CHT=32.
// P is never materialized: chunk decay == exp(a[s]*sdt) identically.
// LDS: As (32x264 bf16) + Db (32x44 f32) = 22.5 KB.
// ---------------------------------------------------------------------------
#define PADD 44
__global__ __launch_bounds__(256) void k_xp_scan1(
        const bf16_t* __restrict__ u_pre, const bf16_t* __restrict__ xwb,
        const float* __restrict__ cw, const float* __restrict__ cb,
        const float* __restrict__ dtw, const float* __restrict__ dtb,
        const float* __restrict__ Alog,
        float* __restrict__ dbl, float* __restrict__ Q,
        float* __restrict__ sdtb) {
    __shared__ bf16_t As[CHT * PADI];  // 16896 B
    __shared__ float  Db[CHT * PADD];  // 5632 B
    int tid = threadIdx.x;
    size_t tokBase = (size_t)blockIdx.x * CHT;
    int b  = (int)(tokBase >> 13);
    int p0 = (int)(tokBase & (Lz - 1));
    int c  = p0 >> 5;

    // --- phase A: depthwise conv(k=4)+SiLU from u_pre into As ---
    {
        int d = tid;
        float w0 = cw[d*4+0], w1 = cw[d*4+1], w2 = cw[d*4+2], w3 = cw[d*4+3];
        float bb = cb[d];
        size_t base = tokBase * DI + d;
        float x3 = (p0 >= 3) ? bf2f(u_pre[base - 3*DI]) : 0.f;
        float x2 = (p0 >= 2) ? bf2f(u_pre[base - 2*DI]) : 0.f;
        float x1 = (p0 >= 1) ? bf2f(u_pre[base - 1*DI]) : 0.f;
#pragma unroll 4
        for (int t = 0; t < CHT; ++t) {
            float x0 = bf2f(u_pre[base + (size_t)t * DI]);
            float conv = bb + w0*x3 + w1*x2 + w2*x1 + w3*x0;
            float sil = conv * fast_rcp(1.f + __expf(-conv));
            As[t * PADI + d] = f2bf(sil);
            x3 = x2; x2 = x1; x1 = x0;
        }
    }
    __syncthreads();

    // --- phase B: GEMM dbl[32 x 40] = u @ xw^T (N padded to 64) ---
    {
        int wave = tid >> 6, lane = tid & 63;
        int lr = lane & 15, lq = lane >> 4;
        int wm = (wave & 1) * 16;
        int wn = (wave >> 1) * 32;
        f4 zf = {0.f, 0.f, 0.f, 0.f};
        f4 acc[2];
        acc[0] = zf; acc[1] = zf;
        const bf16_t* Bp = xwb + (size_t)(wn + lr) * DI + lq * 8;
#pragma unroll
        for (int kk = 0; kk < DI; kk += 32) {
            bf8 af = *(const bf8*)&As[(wm + lr) * PADI + lq * 8 + kk];
            bf8 bq[2];
#pragma unroll
            for (int ni = 0; ni < 2; ++ni)
                bq[ni] = *(const bf8*)(Bp + (size_t)ni * 16 * DI + kk);
#pragma unroll
            for (int ni = 0; ni < 2; ++ni)
                acc[ni] = __builtin_amdgcn_mfma_f32_16x16x32_bf16(
                    af, bq[ni], acc[ni], 0, 0, 0);
        }
#pragma unroll
        for (int ni = 0; ni < 2; ++ni)
#pragma unroll
            for (int r = 0; r < 4; ++r) {
                int col = wn + ni * 16 + lr;
                if (col < NDBL)
                    Db[(wm + lq * 4 + r) * PADD + col] = acc[ni][r];
            }
    }
    __syncthreads();
    // dbl -> global (needed by k_scan3_out)
    for (int i = tid; i < CHT * NDBL; i += 256) {
        int row = i / NDBL, col = i - row * NDBL;
        dbl[(tokBase + row) * NDBL + col] = Db[row * PADD + col];
    }

    // --- phase C: scan1 over the chunk (thread = d) ---
    {
        int d = tid;
        float w[DTR];
#pragma unroll
        for (int r = 0; r < DTR; ++r) w[r] = dtw[d * DTR + r];
        float bb = dtb[d];
        float a[DS], q[DS];
        const float4* ap = (const float4*)(Alog + d * DS);
#pragma unroll
        for (int s4 = 0; s4 < 4; ++s4) {
            float4 av = ap[s4];
            a[s4*4+0] = -__expf(av.x); a[s4*4+1] = -__expf(av.y);
            a[s4*4+2] = -__expf(av.z); a[s4*4+3] = -__expf(av.w);
        }
#pragma unroll
        for (int s = 0; s < DS; ++s) q[s] = 0.f;
        float a0 = a[0];
        bool fast = true;
#pragma unroll
        for (int s = 1; s < DS; ++s) {
            float ref = a0 * (float)(s + 1);
            fast = fast && (fabsf(a[s] - ref) <= 1e-5f * fabsf(ref) + 1e-7f);
        }
        float sdt = 0.f;
        if (fast) {
#pragma unroll 4
            for (int t = 0; t < CHT; ++t) {
                float4 r0 = *(const float4*)&Db[t * PADD + 0];
                float4 r1 = *(const float4*)&Db[t * PADD + 4];
                float xv = bb + r0.x*w[0] + r0.y*w[1] + r0.z*w[2] + r0.w*w[3]
                              + r1.x*w[4] + r1.y*w[5] + r1.z*w[6] + r1.w*w[7];
                float dtv = (xv > 20.f) ? xv : __logf(1.f + __expf(xv));
                sdt += dtv;
                float uv = bf2f(As[t * PADI + d]);
                float dtu = dtv * uv;
                float e1 = __expf(dtv * a0);
                float dA[DS];
                pow_tree(e1, dA);
                float bv[DS];
                *(float4*)&bv[0]  = *(const float4*)&Db[t * PADD + 8];
                *(float4*)&bv[4]  = *(const float4*)&Db[t * PADD + 12];
                *(float4*)&bv[8]  = *(const float4*)&Db[t * PADD + 16];
                *(float4*)&bv[12] = *(const float4*)&Db[t * PADD + 20];
#pragma unroll
                for (int s = 0; s < DS; ++s)
                    q[s] = q[s] * dA[s] + dtu * bv[s];
            }
        } else {
            for (int t = 0; t < CHT; ++t) {
                float4 r0 = *(const float4*)&Db[t * PADD + 0];
                float4 r1 = *(const float4*)&Db[t * PADD + 4];
                float xv = bb + r0.x*w[0] + r0.y*w[1] + r0.z*w[2] + r0.w*w[3]
                              + r1.x*w[4] + r1.y*w[5] + r1.z*w[6] + r1.w*w[7];
                float dtv = (xv > 20.f) ? xv : __logf(1.f + __expf(xv));
                sdt += dtv;
                float uv = bf2f(As[t * PADI + d]);
                float dtu = dtv * uv;
                float bv[DS];
                *(float4*)&bv[0]  = *(const float4*)&Db[t * PADD + 8];
                *(float4*)&bv[4]  = *(const float4*)&Db[t * PADD + 12];
                *(float4*)&bv[8]  = *(const float4*)&Db[t * PADD + 16];
                *(float4*)&bv[12] = *(const float4*)&Db[t * PADD + 20];
#pragma unroll
                for (int s = 0; s < DS; ++s) {
                    float dA = __expf(dtv * a[s]);
                    q[s] = q[s] * dA + dtu * bv[s];
                }
            }
        }
        size_t o = ((size_t)(b * NCH + c) * DI + d) * DS;
#pragma unroll
        for (int s = 0; s < DS; s += 4)
            *(float4*)&Q[o + s] = make_float4(q[s], q[s+1], q[s+2], q[s+3]);
        sdtb[(size_t)(b * NCH + c) * DI + d] = sdt;
    }
}

// ---------------------------------------------------------------------------
// Phase 2: scan chunk summaries. Decay reconstructed from sdt (P == exp(a*sdt)
// exactly, both paths). Q[c] overwritten in place with the chunk entry state.
// 16-deep load prefetch.
// ---------------------------------------------------------------------------
__global__ __launch_bounds__(256) void k_scan2(float* __restrict__ Q,
                                               const float* __restrict__ sdtb,
                                               const float* __restrict__ Alog) {
    int gid = blockIdx.x * 256 + threadIdx.x;   // Bz*DI*DS = 32768 threads
    int b = gid >> 12, r = gid & 4095;          // r = d*16 + s
    int d = r >> 4, s = r & 15;
    float a = -__expf(Alog[d * DS + s]);
    const size_t stride = (size_t)DI * DS;
    size_t base = (size_t)b * NCH * stride + r;
    const float* sp = sdtb + (size_t)b * NCH * DI + d;
    float hh = 0.f;
    for (int g = 0; g < NCH / 16; ++g) {
        float qq[16], ee[16];
#pragma unroll
        for (int j = 0; j < 16; ++j)
            qq[j] = Q[base + (size_t)(g * 16 + j) * stride];
#pragma unroll
        for (int j = 0; j < 16; ++j)
            ee[j] = __expf(a * sp[(size_t)(g * 16 + j) * DI]);
#pragma unroll
        for (int j = 0; j < 16; ++j) {
            size_t o = base + (size_t)(g * 16 + j) * stride;
            Q[o] = hh;
            hh = ee[j] * hh + qq[j];
        }
    }
}

// ---------------------------------------------------------------------------
// FUSED: scan3 (replay with entry state, conv recompute, gating) -> y tile in
// LDS -> out-GEMM h += y @ out_w^T. CHT=32; fp32 epilogue aliases the y tile.
// LDS total ~22 KB.
// ---------------------------------------------------------------------------
__global__ __launch_bounds__(256) void k_scan3_out(
        const float* __restrict__ dbl, const bf16_t* __restrict__ u_pre,
        const bf16_t* __restrict__ z,
        const float* __restrict__ cw, const float* __restrict__ cb,
        const float* __restrict__ dtw, const float* __restrict__ dtb,
        const float* __restrict__ Alog, const float* __restrict__ Dpv,
        const float* __restrict__ H0, const bf16_t* __restrict__ owb,
        float* __restrict__ h) {
    __shared__ float epit[CHT * 132];  // 16896 B; aliased as bf16 y tile
    __shared__ float Dt8[CHT * 8];
    __shared__ float Bs[CHT * DS];
    __shared__ float Cs[CHT * DS];
    bf16_t* yt = (bf16_t*)epit;        // CHT x PADI bf16, same bytes

    int tid = threadIdx.x;
    size_t tokBase = (size_t)blockIdx.x * CHT;
    int b  = (int)(tokBase >> 13);
    int p0 = (int)(tokBase & (Lz - 1));
    int c  = p0 >> 5;

    for (int i = tid; i < CHT * NDBL; i += 256) {
        float v = dbl[tokBase * NDBL + i];
        int t = i / NDBL, col = i - t * NDBL;
        if (col < DTR)            Dt8[t * 8 + col] = v;
        else if (col < DTR + DS)  Bs[t * DS + (col - DTR)] = v;
        else                      Cs[t * DS + (col - DTR - DS)] = v;
    }
    __syncthreads();

    // --- scan phase (thread = d) ---
    {
        int d = tid;
        float cw0 = cw[d*4+0], cw1 = cw[d*4+1], cw2 = cw[d*4+2], cw3 = cw[d*4+3];
        float cbb = cb[d];
        float w[DTR];
#pragma unroll
        for (int r = 0; r < DTR; ++r) w[r] = dtw[d * DTR + r];
        float bb = dtb[d];
        float a[DS], hh[DS];
        const float4* ap = (const float4*)(Alog + d * DS);
#pragma unroll
        for (int s4 = 0; s4 < 4; ++s4) {
            float4 av = ap[s4];
            a[s4*4+0] = -__expf(av.x); a[s4*4+1] = -__expf(av.y);
            a[s4*4+2] = -__expf(av.z); a[s4*4+3] = -__expf(av.w);
        }
        size_t ho = ((size_t)(b * NCH + c) * DI + d) * DS;
#pragma unroll
        for (int s = 0; s < DS; s += 4) {
            float4 hv = *(const float4*)&H0[ho + s];
            hh[s] = hv.x; hh[s+1] = hv.y; hh[s+2] = hv.z; hh[s+3] = hv.w;
        }
        float a0 = a[0];
        bool fast = true;
#pragma unroll
        for (int s = 1; s < DS; ++s) {
            float ref = a0 * (float)(s + 1);
            fast = fast && (fabsf(a[s] - ref) <= 1e-5f * fabsf(ref) + 1e-7f);
        }
        float dp = Dpv[d];
        size_t base = tokBase * DI + d;
        const bf16_t* up = u_pre + base;
        const bf16_t* zp = z + base;
        float x3 = (p0 >= 3) ? bf2f(u_pre[base - 3*DI]) : 0.f;
        float x2 = (p0 >= 2) ? bf2f(u_pre[base - 2*DI]) : 0.f;
        float x1 = (p0 >= 1) ? bf2f(u_pre[base - 1*DI]) : 0.f;
        float uc[4], zc[4];
#pragma unroll
        for (int j = 0; j < 4; ++j) {
            uc[j] = bf2f(up[(size_t)j * DI]);
            zc[j] = bf2f(zp[(size_t)j * DI]);
        }
        for (int g = 0; g < CHT / 4; ++g) {
            float un[4] = {0,0,0,0}, zn[4] = {0,0,0,0};
            if (g + 1 < CHT / 4) {
#pragma unroll
                for (int j = 0; j < 4; ++j) {
                    un[j] = bf2f(up[(size_t)((g + 1) * 4 + j) * DI]);
                    zn[j] = bf2f(zp[(size_t)((g + 1) * 4 + j) * DI]);
                }
            }
            if (fast) {
#pragma unroll
                for (int j = 0; j < 4; ++j) {
                    int t = g * 4 + j;
                    float x0 = uc[j];
                    float conv = cbb + cw0*x3 + cw1*x2 + cw2*x1 + cw3*x0;
                    float uv = conv * fast_rcp(1.f + __expf(-conv));
                    x3 = x2; x2 = x1; x1 = x0;
                    float4 r0 = *(const float4*)&Dt8[t * 8];
                    float4 r1 = *(const float4*)&Dt8[t * 8 + 4];
                    float xv = bb + r0.x*w[0] + r0.y*w[1] + r0.z*w[2] + r0.w*w[3]
                                  + r1.x*w[4] + r1.y*w[5] + r1.z*w[6] + r1.w*w[7];
                    float dtv = (xv > 20.f) ? xv : __logf(1.f + __expf(xv));
                    float zv = zc[j];
                    float dtu = dtv * uv;
                    float e1 = __expf(dtv * a0);
                    float dA[DS];
                    pow_tree(e1, dA);
                    float bv[DS], cv[DS];
                    *(float4*)&bv[0]  = *(const float4*)&Bs[t * DS + 0];
                    *(float4*)&bv[4]  = *(const float4*)&Bs[t * DS + 4];
                    *(float4*)&bv[8]  = *(const float4*)&Bs[t * DS + 8];
                    *(float4*)&bv[12] = *(const float4*)&Bs[t * DS + 12];
                    *(float4*)&cv[0]  = *(const float4*)&Cs[t * DS + 0];
                    *(float4*)&cv[4]  = *(const float4*)&Cs[t * DS + 4];
                    *(float4*)&cv[8]  = *(const float4*)&Cs[t * DS + 8];
                    *(float4*)&cv[12] = *(const float4*)&Cs[t * DS + 12];
                    float y0 = 0.f, y1 = 0.f, y2 = 0.f, y3 = 0.f;
#pragma unroll
                    for (int s = 0; s < DS; s += 4) {
                        hh[s]   = hh[s]   * dA[s]   + dtu * bv[s];
                        hh[s+1] = hh[s+1] * dA[s+1] + dtu * bv[s+1];
                        hh[s+2] = hh[s+2] * dA[s+2] + dtu * bv[s+2];
                        hh[s+3] = hh[s+3] * dA[s+3] + dtu * bv[s+3];
                        y0 += hh[s]   * cv[s];
                        y1 += hh[s+1] * cv[s+1];
                        y2 += hh[s+2] * cv[s+2];
                        y3 += hh[s+3] * cv[s+3];
                    }
                    float y = (y0 + y1) + (y2 + y3);
                    float sil = zv * fast_rcp(1.f + __expf(-zv));
                    yt[t * PADI + d] = f2bf((y + uv * dp) * sil);
                }
            } else {
#pragma unroll
                for (int j = 0; j < 4; ++j) {
                    int t = g * 4 + j;
                    float x0 = uc[j];
                    float conv = cbb + cw0*x3 + cw1*x2 + cw2*x1 + cw3*x0;
                    float uv = conv * fast_rcp(1.f + __expf(-conv));
                    x3 = x2; x2 = x1; x1 = x0;
                    float4 r0 = *(const float4*)&Dt8[t * 8];
                    float4 r1 = *(const float4*)&Dt8[t * 8 + 4];
                    float xv = bb + r0.x*w[0] + r0.y*w[1] + r0.z*w[2] + r0.w*w[3]
                                  + r1.x*w[4] + r1.y*w[5] + r1.z*w[6] + r1.w*w[7];
                    float dtv = (xv > 20.f) ? xv : __logf(1.f + __expf(xv));
                    float zv = zc[j];
                    float dtu = dtv * uv;
                    float bv[DS], cv[DS];
                    *(float4*)&bv[0]  = *(const float4*)&Bs[t * DS + 0];
                    *(float4*)&bv[4]  = *(const float4*)&Bs[t * DS + 4];
                    *(float4*)&bv[8]  = *(const float4*)&Bs[t * DS + 8];
                    *(float4*)&bv[12] = *(const float4*)&Bs[t * DS + 12];
                    *(float4*)&cv[0]  = *(const float4*)&Cs[t * DS + 0];
                    *(float4*)&cv[4]  = *(const float4*)&Cs[t * DS + 4];
                    *(float4*)&cv[8]  = *(const float4*)&Cs[t * DS + 8];
                    *(float4*)&cv[12] = *(const float4*)&Cs[t * DS + 12];
                    float y = 0.f;
#pragma unroll
                    for (int s = 0; s < DS; ++s) {
                        float dA = __expf(dtv * a[s]);
                        hh[s] = hh[s] * dA + dtu * bv[s];
                        y += hh[s] * cv[s];
                    }
                    float sil = zv * fast_rcp(1.f + __expf(-zv));
                    yt[t * PADI + d] = f2bf((y + uv * dp) * sil);
                }
            }
#pragma unroll
            for (int j = 0; j < 4; ++j) { uc[j] = un[j]; zc[j] = zn[j]; }
        }
    }
    __syncthreads();

    // --- out-GEMM: h[32 x 128] += y[32 x 256] @ out_w^T ---
    int wave = tid >> 6, lane = tid & 63;
    int lr = lane & 15, lq = lane >> 4;
    int wm = (wave & 1) * 16;
    int wn = (wave >> 1) * 64;
    f4 zf = {0.f, 0.f, 0.f, 0.f};
    f4 acc[4];
#pragma unroll
    for (int ni = 0; ni < 4; ++ni) acc[ni] = zf;
    const bf16_t* Bp = owb + (size_t)(wn + lr) * DI + lq * 8;
#pragma unroll
    for (int kk = 0; kk < DI; kk += 32) {
        bf8 af = *(const bf8*)&yt[(wm + lr) * PADI + lq * 8 + kk];
        bf8 bq[4];
#pragma unroll
        for (int ni = 0; ni < 4; ++ni)
            bq[ni] = *(const bf8*)(Bp + (size_t)ni * 16 * DI + kk);
#pragma unroll
        for (int ni = 0; ni < 4; ++ni)
            acc[ni] = __builtin_amdgcn_mfma_f32_16x16x32_bf16(
                af, bq[ni], acc[ni], 0, 0, 0);
    }
    __syncthreads();   // all y reads done; epit may be overwritten
#pragma unroll
    for (int ni = 0; ni < 4; ++ni)
#pragma unroll
        for (int r = 0; r < 4; ++r)
            epit[(wm + lq * 4 + r) * 132 + wn + ni * 16 + lr] = acc[ni][r];
    __syncthreads();
    for (int i = tid; i < CHT * 32; i += 256) {
        int row = i >> 5, col = (i & 31) * 4;
        float4 v = *(const float4*)&epit[row * 132 + col];
        float4 old = *(const float4*)&h[(tokBase + row) * DM + col];
        old.x += v.x; old.y += v.y; old.z += v.z; old.w += v.w;
        *(float4*)&h[(tokBase + row) * DM + col] = old;
    }
}

// ---------------------------------------------------------------------------
__global__ __launch_bounds__(256) void k_final(float* __restrict__ h,
                                               const float* __restrict__ w,
                                               const float* __restrict__ bias,
                                               float* __restrict__ hg) {
    __shared__ float sbuf[DM];
    int t    = blockIdx.x * 16 + (threadIdx.x >> 4);
    int lane = threadIdx.x & 15;
    int b    = t >> 13;
    if (threadIdx.x < DM) sbuf[threadIdx.x] = 0.f;
    __syncthreads();
    float4* hp = (float4*)(h + (size_t)t * DM + lane * 8);
    float4 v0 = hp[0], v1 = hp[1];
    float s = v0.x + v0.y + v0.z + v0.w + v1.x + v1.y + v1.z + v1.w;
    float q = v0.x*v0.x + v0.y*v0.y + v0.z*v0.z + v0.w*v0.w +
              v1.x*v1.x + v1.y*v1.y + v1.z*v1.z + v1.w*v1.w;
#pragma unroll
    for (int off = 1; off < 16; off <<= 1) {
        s += __shfl_xor(s, off);
        q += __shfl_xor(q, off);
    }
    float mean = s * (1.f / DM);
    float var  = q * (1.f / DM) - mean * mean;
    float rstd = rsqrtf(var + 1e-5f);
    const float4* wp = (const float4*)(w + lane * 8);
    const float4* bp = (const float4*)(bias + lane * 8);
    float4 w0 = wp[0], w1 = wp[1], b0 = bp[0], b1 = bp[1];
    float4 o0, o1;
    o0.x = (v0.x - mean) * rstd * w0.x + b0.x;
    o0.y = (v0.y - mean) * rstd * w0.y + b0.y;
    o0.z = (v0.z - mean) * rstd * w0.z + b0.z;
    o0.w = (v0.w - mean) * rstd * w0.w + b0.w;
    o1.x = (v1.x - mean) * rstd * w1.x + b1.x;
    o1.y = (v1.y - mean) * rstd * w1.y + b1.y;
    o1.z = (v1.z - mean) * rstd * w1.z + b1.z;
    o1.w = (v1.w - mean) * rstd * w1.w + b1.w;
    hp[0] = o0; hp[1] = o1;
    int dbase = lane * 8;
    atomicAdd(&sbuf[dbase + 0], o0.x); atomicAdd(&sbuf[dbase + 1], o0.y);
    atomicAdd(&sbuf[dbase + 2], o0.z); atomicAdd(&sbuf[dbase + 3], o0.w);
    atomicAdd(&sbuf[dbase + 4], o1.x); atomicAdd(&sbuf[dbase + 5], o1.y);
    atomicAdd(&sbuf[dbase + 6], o1.z); atomicAdd(&sbuf[dbase + 7], o1.w);
    __syncthreads();
    if (threadIdx.x < DM)
        atomicAdd(&hg[b * DM + threadIdx.x], sbuf[threadIdx.x] * (1.f / Lz));
}

// ---------------------------------------------------------------------------
extern "C" void kernel_launch(void* const* d_in, const int* in_sizes, int n_in,
                              void* d_out, int out_size, void* d_ws, size_t ws_size,
                              hipStream_t stream) {
    const float* x       = (const float*)d_in[0];
    const float* proj_w  = (const float*)d_in[1];
    const float* proj_b  = (const float*)d_in[2];
    const float* ln_w    = (const float*)d_in[3];
    const float* ln_b    = (const float*)d_in[4];
    const float* in_w    = (const float*)d_in[5];
    const float* conv_w  = (const float*)d_in[6];
    const float* conv_b  = (const float*)d_in[7];
    const float* xproj_w = (const float*)d_in[8];
    const float* dt_w    = (const float*)d_in[9];
    const float* dt_b    = (const float*)d_in[10];
    const float* A_log   = (const float*)d_in[11];
    const float* Dp      = (const float*)d_in[12];
    const float* out_w   = (const float*)d_in[13];
    const float* lnout_w = (const float*)d_in[14];
    const float* lnout_b = (const float*)d_in[15];

    float* out = (float*)d_out;
    float* h   = out;                        // [BL][128] lives in d_out
    float* hg  = out + (size_t)BLz * DM;     // [B][128]

    // Workspace layout (~125 MiB).
    char* ws = (char*)d_ws;
    bf16_t* xn    = (bf16_t*)(ws);                    // 16 MiB
    bf16_t* u_pre = (bf16_t*)(ws + 16777216ULL);      // 32 MiB
    bf16_t* z     = (bf16_t*)(ws + 50331648ULL);      // 32 MiB
    float*  dbl   = (float*) (ws + 83886080ULL);      // 10 MiB
    float*  Q     = (float*) (ws + 94371840ULL);      // 32 MiB (Q -> entry states in place)
    float*  sdtb  = (float*) (ws + 127926272ULL);     // 2 MiB
    bf16_t* inwb  = (bf16_t*)(ws + 130023424ULL);     // 512 KiB
    bf16_t* owb   = (bf16_t*)(ws + 130547712ULL);     // 256 KiB
    bf16_t* xwb   = (bf16_t*)(ws + 130809856ULL);     // 128 KiB

    k_zero_hg<<<4, 256, 0, stream>>>(hg);
    k_wconv<<<1024, 256, 0, stream>>>(in_w, out_w, xproj_w, inwb, owb, xwb);
    k_inproj<<<BLz / 2, 256, 0, stream>>>(x, proj_w, proj_b, h);

    for (int i = 0; i < DEPTHN; ++i) {
        k_ln<<<BLz / 16, 256, 0, stream>>>(h, ln_w + i * DM, ln_b + i * DM, xn);
        k_mfma_in<<<dim3(BLz / 64, 2), 256, 0, stream>>>(
            xn, inwb + (size_t)i * 512 * DM, u_pre, z);
        k_xp_scan1<<<BLz / CHT, 256, 0, stream>>>(
            u_pre, xwb + (size_t)i * 64 * DI,
            conv_w + i * DI * 4, conv_b + i * DI,
            dt_w + i * DI * DTR, dt_b + i * DI, A_log + i * DI * DS,
            dbl, Q, sdtb);
        k_scan2<<<(Bz * DI * DS) / 256, 256, 0, stream>>>(
            Q, sdtb, A_log + i * DI * DS);
        k_scan3_out<<<BLz / CHT, 256, 0, stream>>>(
            dbl, u_pre, z,
            conv_w + i * DI * 4, conv_b + i * DI,
            dt_w + i * DI * DTR, dt_b + i * DI,
            A_log + i * DI * DS, Dp + i * DI, Q,
            owb + (size_t)i * DM * DI, h);
    }

    k_final<<<BLz / 16, 256, 0, stream>>>(h, lnout_w, lnout_b, hg);
}

// Round 7
// 1001.147 us; speedup vs baseline: 1.1264x; 1.1264x over previous
//
#include <hip/hip_runtime.h>
#include <hip/hip_bf16.h>
#include <math.h>

// Problem constants (MambaEncoder)
#define Bz     8
#define Lz     8192
#define DM     128      // d_model
#define DI     256      // d_inner
#define DS     16       // d_state
#define DTR    8        // dt_rank
#define NDBL   40       // DTR + 2*DS
#define DEPTHN 4
#define BLz    (Bz*Lz)  // 65536 tokens
#define CHT    64       // scan chunk length == M-tile
#define NCH    (Lz/CHT) // 128 chunks per sequence
#define PADI   264      // bf16 tile row stride (16B-aligned, bank-stride 4)
#define PADD   44       // f32 Db row stride

typedef unsigned short bf16_t;
typedef __attribute__((ext_vector_type(8))) __bf16 bf8;
typedef __attribute__((ext_vector_type(4))) float f4;
typedef __attribute__((ext_vector_type(8))) unsigned short us8;

__device__ __forceinline__ float bf2f(bf16_t u) {
    return __uint_as_float(((unsigned)u) << 16);
}
__device__ __forceinline__ bf16_t f2bf(float f) {
    unsigned u = __float_as_uint(f);
    u = u + 0x7FFFu + ((u >> 16) & 1u);   // round-to-nearest-even
    return (bf16_t)(u >> 16);
}
__device__ __forceinline__ float fast_rcp(float x) {
    return __builtin_amdgcn_rcpf(x);
}

// dA power tree: dA[s] = e1^(s+1), depth 4.
__device__ __forceinline__ void pow_tree(float e1, float dA[DS]) {
    float e2 = e1 * e1, e3 = e2 * e1, e4 = e2 * e2;
    float e8 = e4 * e4;
    dA[0] = e1;       dA[1] = e2;       dA[2] = e3;       dA[3] = e4;
    dA[4] = e4 * e1;  dA[5] = e4 * e2;  dA[6] = e4 * e3;  dA[7] = e8;
    dA[8] = e8 * e1;  dA[9] = e8 * e2;  dA[10] = e8 * e3; dA[11] = e8 * e4;
    dA[12] = e8 * dA[4]; dA[13] = e8 * dA[5]; dA[14] = e8 * dA[6];
    dA[15] = e8 * e8;
}

// ---------------------------------------------------------------------------
__global__ void k_zero_hg(float* __restrict__ hg) {
    int i = blockIdx.x * 256 + threadIdx.x;
    if (i < Bz * DM) hg[i] = 0.f;
}

// ---------------------------------------------------------------------------
// Convert weights fp32 -> bf16 (xproj padded from 40 to 64 rows with zeros).
// ---------------------------------------------------------------------------
__global__ __launch_bounds__(256) void k_wconv(const float* __restrict__ inw,
                                               const float* __restrict__ ow,
                                               const float* __restrict__ xw,
                                               bf16_t* __restrict__ inwb,
                                               bf16_t* __restrict__ owb,
                                               bf16_t* __restrict__ xwb) {
    int i = blockIdx.x * 256 + threadIdx.x;
    if (i < DEPTHN * 512 * DM) inwb[i] = f2bf(inw[i]);
    if (i < DEPTHN * DM * DI)  owb[i]  = f2bf(ow[i]);
    if (i < DEPTHN * 64 * DI) {
        int layer = i >> 14, rk = i & 16383, r = rk >> 8, k = rk & 255;
        xwb[i] = (r < NDBL) ? f2bf(xw[((size_t)layer * NDBL + r) * DI + k]) : (bf16_t)0;
    }
}

// ---------------------------------------------------------------------------
__global__ __launch_bounds__(256) void k_inproj(const float* __restrict__ x,
                                                const float* __restrict__ pw,
                                                const float* __restrict__ pb,
                                                float* __restrict__ h) {
    int t = blockIdx.x * 2 + (threadIdx.x >> 7);
    int d = threadIdx.x & 127;
    int b = t >> 13, l = t & (Lz - 1);
    float acc = pb[d];
#pragma unroll
    for (int c = 0; c < 3; ++c)
        acc += x[(size_t)(b * 3 + c) * Lz + l] * pw[d * 3 + c];
    h[(size_t)t * DM + d] = acc;
}

// ---------------------------------------------------------------------------
// FUSED: LayerNorm (64 rows) -> in-proj GEMM [64x512] -> u_pre (raw) + zs
// (silu pre-applied). xn tile lives only in LDS. One block per 64 tokens.
// ---------------------------------------------------------------------------
__global__ __launch_bounds__(256) void k_lnin(const float* __restrict__ h,
                                              const float* __restrict__ lw,
                                              const float* __restrict__ lb,
                                              const bf16_t* __restrict__ inwb,
                                              bf16_t* __restrict__ u_pre,
                                              bf16_t* __restrict__ zs) {
    __shared__ bf16_t sm[64 * PADI];     // 33792 B; xs view (stride 136) first
    bf16_t* xs = sm;                      // 64 x 136 region
    int tid = threadIdx.x;
    int mBase = blockIdx.x * 64;

    // --- LayerNorm: 4 passes of 16 rows, 16 lanes/row ---
#pragma unroll
    for (int p = 0; p < 4; ++p) {
        int row = p * 16 + (tid >> 4);
        int lane = tid & 15;
        const float4* hp = (const float4*)(h + (size_t)(mBase + row) * DM + lane * 8);
        float4 v0 = hp[0], v1 = hp[1];
        float s = v0.x + v0.y + v0.z + v0.w + v1.x + v1.y + v1.z + v1.w;
        float q = v0.x*v0.x + v0.y*v0.y + v0.z*v0.z + v0.w*v0.w +
                  v1.x*v1.x + v1.y*v1.y + v1.z*v1.z + v1.w*v1.w;
#pragma unroll
        for (int off = 1; off < 16; off <<= 1) {
            s += __shfl_xor(s, off);
            q += __shfl_xor(q, off);
        }
        float mean = s * (1.f / DM);
        float var  = q * (1.f / DM) - mean * mean;
        float rstd = rsqrtf(var + 1e-5f);
        const float4* wp = (const float4*)(lw + lane * 8);
        const float4* bp = (const float4*)(lb + lane * 8);
        float4 w0 = wp[0], w1 = wp[1], b0 = bp[0], b1 = bp[1];
        ushort4 o0, o1;
        o0.x = f2bf((v0.x - mean) * rstd * w0.x + b0.x);
        o0.y = f2bf((v0.y - mean) * rstd * w0.y + b0.y);
        o0.z = f2bf((v0.z - mean) * rstd * w0.z + b0.z);
        o0.w = f2bf((v0.w - mean) * rstd * w0.w + b0.w);
        o1.x = f2bf((v1.x - mean) * rstd * w1.x + b1.x);
        o1.y = f2bf((v1.y - mean) * rstd * w1.y + b1.y);
        o1.z = f2bf((v1.z - mean) * rstd * w1.z + b1.z);
        o1.w = f2bf((v1.w - mean) * rstd * w1.w + b1.w);
        *(ushort4*)&xs[row * 136 + lane * 8]     = o0;
        *(ushort4*)&xs[row * 136 + lane * 8 + 4] = o1;
    }
    __syncthreads();

    // --- GEMM: [64 x 512] = xs[64 x 128] @ in_w^T; wave n-slice 128 ---
    int wave = tid >> 6, lane = tid & 63;
    int lr = lane & 15, lq = lane >> 4;
    int wn = wave * 128;
    f4 zf = {0.f, 0.f, 0.f, 0.f};
    f4 acc[4][8];
#pragma unroll
    for (int mi = 0; mi < 4; ++mi)
#pragma unroll
        for (int ni = 0; ni < 8; ++ni) acc[mi][ni] = zf;
    const bf16_t* Bp = inwb + (size_t)(wn + lr) * DM + lq * 8;
#pragma unroll
    for (int kk = 0; kk < DM; kk += 32) {
        bf8 af[4], bq[8];
#pragma unroll
        for (int mi = 0; mi < 4; ++mi)
            af[mi] = *(const bf8*)&xs[(mi * 16 + lr) * 136 + lq * 8 + kk];
#pragma unroll
        for (int ni = 0; ni < 8; ++ni)
            bq[ni] = *(const bf8*)(Bp + (size_t)ni * 16 * DM + kk);
#pragma unroll
        for (int mi = 0; mi < 4; ++mi)
#pragma unroll
            for (int ni = 0; ni < 8; ++ni)
                acc[mi][ni] = __builtin_amdgcn_mfma_f32_16x16x32_bf16(
                    af[mi], bq[ni], acc[mi][ni], 0, 0, 0);
    }
    __syncthreads();   // xs dead; sm reusable as 64x264 output tile

    // --- epilogue pass 1: u (cols 0..255, waves 0,1), raw bf16 ---
    if (wave < 2) {
#pragma unroll
        for (int mi = 0; mi < 4; ++mi)
#pragma unroll
            for (int ni = 0; ni < 8; ++ni)
#pragma unroll
                for (int r = 0; r < 4; ++r)
                    sm[(mi * 16 + lq * 4 + r) * PADI + wn + ni * 16 + lr] =
                        f2bf(acc[mi][ni][r]);
    }
    __syncthreads();
    for (int i = tid; i < 2048; i += 256) {
        int row = i >> 5, col = (i & 31) * 8;
        us8 v = *(const us8*)&sm[row * PADI + col];
        *(us8*)&u_pre[(size_t)(mBase + row) * DI + col] = v;
    }
    __syncthreads();
    // --- epilogue pass 2: zs = silu(z) (cols 256..511, waves 2,3) ---
    if (wave >= 2) {
#pragma unroll
        for (int mi = 0; mi < 4; ++mi)
#pragma unroll
            for (int ni = 0; ni < 8; ++ni)
#pragma unroll
                for (int r = 0; r < 4; ++r) {
                    float v = acc[mi][ni][r];
                    float sil = v * fast_rcp(1.f + __expf(-v));
                    sm[(mi * 16 + lq * 4 + r) * PADI + (wn - 256) + ni * 16 + lr] =
                        f2bf(sil);
                }
    }
    __syncthreads();
    for (int i = tid; i < 2048; i += 256) {
        int row = i >> 5, col = (i & 31) * 8;
        us8 v = *(const us8*)&sm[row * PADI + col];
        *(us8*)&zs[(size_t)(mBase + row) * DI + col] = v;
    }
}

// ---------------------------------------------------------------------------
// FUSED: coalesced u_pre staging -> in-LDS conv+SiLU -> xproj GEMM ->
// scan1 with local-y: ybase = C·h_local + u·Dp (bf16), Q, sdt, dtc (dt+C).
// ---------------------------------------------------------------------------
__global__ __launch_bounds__(256, 3) void k_xp_scan1(
        const bf16_t* __restrict__ u_pre, const bf16_t* __restrict__ xwb,
        const float* __restrict__ cw, const float* __restrict__ cb,
        const float* __restrict__ dtw, const float* __restrict__ dtb,
        const float* __restrict__ Alog, const float* __restrict__ Dpv,
        float* __restrict__ dtc, float* __restrict__ Q,
        float* __restrict__ sdtb, bf16_t* __restrict__ ybase) {
    __shared__ bf16_t As[CHT * PADI];  // 33792 B
    __shared__ float  Db[CHT * PADD];  // 11264 B
    int tid = threadIdx.x;
    size_t tokBase = (size_t)blockIdx.x * CHT;
    int b  = (int)(tokBase >> 13);
    int p0 = (int)(tokBase & (Lz - 1));
    int c  = p0 >> 6;

    // halo (3 tokens before chunk; p0 is 0 or >=64)
    int d = tid;
    float hx3 = 0.f, hx2 = 0.f, hx1 = 0.f;
    if (p0 != 0) {
        size_t hb = tokBase * DI + d;
        hx3 = bf2f(u_pre[hb - 3 * DI]);
        hx2 = bf2f(u_pre[hb - 2 * DI]);
        hx1 = bf2f(u_pre[hb - 1 * DI]);
    }
    // coalesced staging of raw u_pre tile
    for (int i = tid; i < 2048; i += 256) {
        int row = i >> 5, col = (i & 31) * 8;
        us8 v = *(const us8*)&u_pre[(tokBase + row) * DI + col];
        *(us8*)&As[row * PADI + col] = v;
    }
    __syncthreads();

    // --- conv(k=4)+SiLU in place (column-private) ---
    {
        float w0 = cw[d*4+0], w1 = cw[d*4+1], w2 = cw[d*4+2], w3 = cw[d*4+3];
        float bb = cb[d];
        float x3 = hx3, x2 = hx2, x1 = hx1;
#pragma unroll 8
        for (int t = 0; t < CHT; ++t) {
            float x0 = bf2f(As[t * PADI + d]);
            float conv = bb + w0*x3 + w1*x2 + w2*x1 + w3*x0;
            float sil = conv * fast_rcp(1.f + __expf(-conv));
            As[t * PADI + d] = f2bf(sil);
            x3 = x2; x2 = x1; x1 = x0;
        }
    }
    __syncthreads();

    // --- xproj GEMM: Db[64 x 40] = u @ xw^T (N padded to 64) ---
    {
        int wave = tid >> 6, lane = tid & 63;
        int lr = lane & 15, lq = lane >> 4;
        int wm = wave * 16;
        f4 zf = {0.f, 0.f, 0.f, 0.f};
        f4 acc[4];
#pragma unroll
        for (int ni = 0; ni < 4; ++ni) acc[ni] = zf;
        const bf16_t* Bp = xwb + (size_t)lr * DI + lq * 8;
#pragma unroll
        for (int kk = 0; kk < DI; kk += 32) {
            bf8 af = *(const bf8*)&As[(wm + lr) * PADI + lq * 8 + kk];
            bf8 bq[4];
#pragma unroll
            for (int ni = 0; ni < 4; ++ni)
                bq[ni] = *(const bf8*)(Bp + (size_t)ni * 16 * DI + kk);
#pragma unroll
            for (int ni = 0; ni < 4; ++ni)
                acc[ni] = __builtin_amdgcn_mfma_f32_16x16x32_bf16(
                    af, bq[ni], acc[ni], 0, 0, 0);
        }
#pragma unroll
        for (int ni = 0; ni < 4; ++ni)
#pragma unroll
            for (int r = 0; r < 4; ++r) {
                int col = ni * 16 + lr;
                if (col < NDBL)
                    Db[(wm + lq * 4 + r) * PADD + col] = acc[ni][r];
            }
    }
    __syncthreads();
    // dtc (dt cols 0..7 + C cols 24..39 -> 24 cols) to global
    for (int i = tid; i < CHT * 24; i += 256) {
        int row = i / 24, cc = i - row * 24;
        dtc[(tokBase + row) * 24 + cc] = Db[row * PADD + (cc < 8 ? cc : cc + 16)];
    }

    // --- scan1 + local y ---
    {
        float w[DTR];
#pragma unroll
        for (int r = 0; r < DTR; ++r) w[r] = dtw[d * DTR + r];
        float bb = dtb[d];
        float dp = Dpv[d];
        float a[DS], q[DS];
        const float4* ap = (const float4*)(Alog + d * DS);
#pragma unroll
        for (int s4 = 0; s4 < 4; ++s4) {
            float4 av = ap[s4];
            a[s4*4+0] = -__expf(av.x); a[s4*4+1] = -__expf(av.y);
            a[s4*4+2] = -__expf(av.z); a[s4*4+3] = -__expf(av.w);
        }
#pragma unroll
        for (int s = 0; s < DS; ++s) q[s] = 0.f;
        float a0 = a[0];
        bool fast = true;
#pragma unroll
        for (int s = 1; s < DS; ++s) {
            float ref = a0 * (float)(s + 1);
            fast = fast && (fabsf(a[s] - ref) <= 1e-5f * fabsf(ref) + 1e-7f);
        }
        float sdt = 0.f;
        bf16_t* yp = ybase + tokBase * DI + d;
        if (fast) {
#pragma unroll 4
            for (int t = 0; t < CHT; ++t) {
                float4 r0 = *(const float4*)&Db[t * PADD + 0];
                float4 r1 = *(const float4*)&Db[t * PADD + 4];
                float xv = bb + r0.x*w[0] + r0.y*w[1] + r0.z*w[2] + r0.w*w[3]
                              + r1.x*w[4] + r1.y*w[5] + r1.z*w[6] + r1.w*w[7];
                float dtv = (xv > 20.f) ? xv : __logf(1.f + __expf(xv));
                sdt += dtv;
                float uv = bf2f(As[t * PADI + d]);
                float dtu = dtv * uv;
                float e1 = __expf(dtv * a0);
                float dA[DS];
                pow_tree(e1, dA);
                float bv[DS], cv[DS];
                *(float4*)&bv[0]  = *(const float4*)&Db[t * PADD + 8];
                *(float4*)&bv[4]  = *(const float4*)&Db[t * PADD + 12];
                *(float4*)&bv[8]  = *(const float4*)&Db[t * PADD + 16];
                *(float4*)&bv[12] = *(const float4*)&Db[t * PADD + 20];
                *(float4*)&cv[0]  = *(const float4*)&Db[t * PADD + 24];
                *(float4*)&cv[4]  = *(const float4*)&Db[t * PADD + 28];
                *(float4*)&cv[8]  = *(const float4*)&Db[t * PADD + 32];
                *(float4*)&cv[12] = *(const float4*)&Db[t * PADD + 36];
                float y0 = 0.f, y1 = 0.f, y2 = 0.f, y3 = 0.f;
#pragma unroll
                for (int s = 0; s < DS; s += 4) {
                    q[s]   = q[s]   * dA[s]   + dtu * bv[s];
                    q[s+1] = q[s+1] * dA[s+1] + dtu * bv[s+1];
                    q[s+2] = q[s+2] * dA[s+2] + dtu * bv[s+2];
                    q[s+3] = q[s+3] * dA[s+3] + dtu * bv[s+3];
                    y0 += q[s]   * cv[s];
                    y1 += q[s+1] * cv[s+1];
                    y2 += q[s+2] * cv[s+2];
                    y3 += q[s+3] * cv[s+3];
                }
                float y = (y0 + y1) + (y2 + y3);
                yp[(size_t)t * DI] = f2bf(y + uv * dp);
            }
        } else {
            for (int t = 0; t < CHT; ++t) {
                float4 r0 = *(const float4*)&Db[t * PADD + 0];
                float4 r1 = *(const float4*)&Db[t * PADD + 4];
                float xv = bb + r0.x*w[0] + r0.y*w[1] + r0.z*w[2] + r0.w*w[3]
                              + r1.x*w[4] + r1.y*w[5] + r1.z*w[6] + r1.w*w[7];
                float dtv = (xv > 20.f) ? xv : __logf(1.f + __expf(xv));
                sdt += dtv;
                float uv = bf2f(As[t * PADI + d]);
                float dtu = dtv * uv;
                float bv[DS], cv[DS];
                *(float4*)&bv[0]  = *(const float4*)&Db[t * PADD + 8];
                *(float4*)&bv[4]  = *(const float4*)&Db[t * PADD + 12];
                *(float4*)&bv[8]  = *(const float4*)&Db[t * PADD + 16];
                *(float4*)&bv[12] = *(const float4*)&Db[t * PADD + 20];
                *(float4*)&cv[0]  = *(const float4*)&Db[t * PADD + 24];
                *(float4*)&cv[4]  = *(const float4*)&Db[t * PADD + 28];
                *(float4*)&cv[8]  = *(const float4*)&Db[t * PADD + 32];
                *(float4*)&cv[12] = *(const float4*)&Db[t * PADD + 36];
                float y = 0.f;
#pragma unroll
                for (int s = 0; s < DS; ++s) {
                    float dA = __expf(dtv * a[s]);
                    q[s] = q[s] * dA + dtu * bv[s];
                    y += q[s] * cv[s];
                }
                yp[(size_t)t * DI] = f2bf(y + uv * dp);
            }
        }
        size_t o = ((size_t)(b * NCH + c) * DI + d) * DS;
#pragma unroll
        for (int s = 0; s < DS; s += 4)
            *(float4*)&Q[o + s] = make_float4(q[s], q[s+1], q[s+2], q[s+3]);
        sdtb[(size_t)(b * NCH + c) * DI + d] = sdt;
    }
}

// ---------------------------------------------------------------------------
// Phase 2: decay from sdt (exact: prod exp(dtv*a) == exp(a*sum dtv)).
// Q[c] overwritten in place with chunk entry state. 16-deep prefetch.
// ---------------------------------------------------------------------------
__global__ __launch_bounds__(256) void k_scan2(float* __restrict__ Q,
                                               const float* __restrict__ sdtb,
                                               const float* __restrict__ Alog) {
    int gid = blockIdx.x * 256 + threadIdx.x;   // Bz*DI*DS threads
    int b = gid >> 12, r = gid & 4095;          // r = d*16 + s
    int d = r >> 4, s = r & 15;
    float a = -__expf(Alog[d * DS + s]);
    const size_t stride = (size_t)DI * DS;
    size_t base = (size_t)b * NCH * stride + r;
    const float* sp = sdtb + (size_t)b * NCH * DI + d;
    float hh = 0.f;
    for (int g = 0; g < NCH / 16; ++g) {
        float qq[16], ee[16];
#pragma unroll
        for (int j = 0; j < 16; ++j)
            qq[j] = Q[base + (size_t)(g * 16 + j) * stride];
#pragma unroll
        for (int j = 0; j < 16; ++j)
            ee[j] = __expf(a * sp[(size_t)(g * 16 + j) * DI]);
#pragma unroll
        for (int j = 0; j < 16; ++j) {
            size_t o = base + (size_t)(g * 16 + j) * stride;
            Q[o] = hh;
            hh = ee[j] * hh + qq[j];
        }
    }
}

// ---------------------------------------------------------------------------
// FUSED: correction + gate -> y tile -> out-GEMM h += y @ out_w^T.
// y_t = ybase_t + sum_s C_t[s]*H0[s]*exp(a[s]*cdt_t); out = y * zs.
// No recurrence, no B rows, no conv. LDS ~39 KB -> 4 blocks/CU.
// ---------------------------------------------------------------------------
__global__ __launch_bounds__(256, 4) void k_corr_out(
        const float* __restrict__ dtc, const bf16_t* __restrict__ ybase,
        const bf16_t* __restrict__ zs,
        const float* __restrict__ dtw, const float* __restrict__ dtb,
        const float* __restrict__ Alog, const float* __restrict__ H0,
        const bf16_t* __restrict__ owb, float* __restrict__ h) {
    __shared__ float epit[CHT * 132];  // 33792 B; aliased as bf16 y tile
    __shared__ float Dt8[CHT * 8];     // 2048 B
    __shared__ float Cs[CHT * DS];     // 4096 B
    bf16_t* yt = (bf16_t*)epit;

    int tid = threadIdx.x;
    size_t tokBase = (size_t)blockIdx.x * CHT;
    int b  = (int)(tokBase >> 13);
    int p0 = (int)(tokBase & (Lz - 1));
    int c  = p0 >> 6;

    for (int i = tid; i < CHT * 24; i += 256) {
        float v = dtc[tokBase * 24 + i];
        int t = i / 24, col = i - t * 24;
        if (col < 8) Dt8[t * 8 + col] = v;
        else         Cs[t * DS + (col - 8)] = v;
    }
    __syncthreads();

    // --- correction + gating (thread = d) ---
    {
        int d = tid;
        float w[DTR];
#pragma unroll
        for (int r = 0; r < DTR; ++r) w[r] = dtw[d * DTR + r];
        float bb = dtb[d];
        float a[DS], gh[DS];
        const float4* ap = (const float4*)(Alog + d * DS);
#pragma unroll
        for (int s4 = 0; s4 < 4; ++s4) {
            float4 av = ap[s4];
            a[s4*4+0] = -__expf(av.x); a[s4*4+1] = -__expf(av.y);
            a[s4*4+2] = -__expf(av.z); a[s4*4+3] = -__expf(av.w);
        }
        size_t ho = ((size_t)(b * NCH + c) * DI + d) * DS;
#pragma unroll
        for (int s = 0; s < DS; s += 4) {
            float4 hv = *(const float4*)&H0[ho + s];
            gh[s] = hv.x; gh[s+1] = hv.y; gh[s+2] = hv.z; gh[s+3] = hv.w;
        }
        float a0 = a[0];
        bool fast = true;
#pragma unroll
        for (int s = 1; s < DS; ++s) {
            float ref = a0 * (float)(s + 1);
            fast = fast && (fabsf(a[s] - ref) <= 1e-5f * fabsf(ref) + 1e-7f);
        }
        const bf16_t* yp = ybase + tokBase * DI + d;
        const bf16_t* zp = zs + tokBase * DI + d;
        float cdt = 0.f;
        float yc[4], zc[4];
#pragma unroll
        for (int j = 0; j < 4; ++j) {
            yc[j] = bf2f(yp[(size_t)j * DI]);
            zc[j] = bf2f(zp[(size_t)j * DI]);
        }
        for (int g = 0; g < CHT / 4; ++g) {
            float yn[4] = {0,0,0,0}, zn[4] = {0,0,0,0};
            if (g + 1 < CHT / 4) {
#pragma unroll
                for (int j = 0; j < 4; ++j) {
                    yn[j] = bf2f(yp[(size_t)((g + 1) * 4 + j) * DI]);
                    zn[j] = bf2f(zp[(size_t)((g + 1) * 4 + j) * DI]);
                }
            }
#pragma unroll
            for (int j = 0; j < 4; ++j) {
                int t = g * 4 + j;
                float4 r0 = *(const float4*)&Dt8[t * 8];
                float4 r1 = *(const float4*)&Dt8[t * 8 + 4];
                float xv = bb + r0.x*w[0] + r0.y*w[1] + r0.z*w[2] + r0.w*w[3]
                              + r1.x*w[4] + r1.y*w[5] + r1.z*w[6] + r1.w*w[7];
                float dtv = (xv > 20.f) ? xv : __logf(1.f + __expf(xv));
                cdt += dtv;
                float cv[DS];
                *(float4*)&cv[0]  = *(const float4*)&Cs[t * DS + 0];
                *(float4*)&cv[4]  = *(const float4*)&Cs[t * DS + 4];
                *(float4*)&cv[8]  = *(const float4*)&Cs[t * DS + 8];
                *(float4*)&cv[12] = *(const float4*)&Cs[t * DS + 12];
                float corr0 = 0.f, corr1 = 0.f, corr2 = 0.f, corr3 = 0.f;
                if (fast) {
                    float e1 = __expf(a0 * cdt);
                    float dA[DS];
                    pow_tree(e1, dA);
#pragma unroll
                    for (int s = 0; s < DS; s += 4) {
                        corr0 += cv[s]   * (gh[s]   * dA[s]);
                        corr1 += cv[s+1] * (gh[s+1] * dA[s+1]);
                        corr2 += cv[s+2] * (gh[s+2] * dA[s+2]);
                        corr3 += cv[s+3] * (gh[s+3] * dA[s+3]);
                    }
                } else {
#pragma unroll
                    for (int s = 0; s < DS; ++s)
                        corr0 += cv[s] * (gh[s] * __expf(a[s] * cdt));
                }
                float y = yc[j] + ((corr0 + corr1) + (corr2 + corr3));
                yt[t * PADI + d] = f2bf(y * zc[j]);
            }
#pragma unroll
            for (int j = 0; j < 4; ++j) { yc[j] = yn[j]; zc[j] = zn[j]; }
        }
    }
    __syncthreads();

    // --- out-GEMM: h[64 x 128] += y[64 x 256] @ out_w^T ---
    int wave = tid >> 6, lane = tid & 63;
    int lr = lane & 15, lq = lane >> 4;
    int wm = wave * 16;
    f4 zf = {0.f, 0.f, 0.f, 0.f};
    f4 acc[8];
#pragma unroll
    for (int ni = 0; ni < 8; ++ni) acc[ni] = zf;
    const bf16_t* Bp = owb + (size_t)lr * DI + lq * 8;
#pragma unroll
    for (int kk = 0; kk < DI; kk += 32) {
        bf8 af = *(const bf8*)&yt[(wm + lr) * PADI + lq * 8 + kk];
        bf8 bq[8];
#pragma unroll
        for (int ni = 0; ni < 8; ++ni)
            bq[ni] = *(const bf8*)(Bp + (size_t)ni * 16 * DI + kk);
#pragma unroll
        for (int ni = 0; ni < 8; ++ni)
            acc[ni] = __builtin_amdgcn_mfma_f32_16x16x32_bf16(
                af, bq[ni], acc[ni], 0, 0, 0);
    }
    __syncthreads();   // yt reads done; epit may be overwritten
#pragma unroll
    for (int ni = 0; ni < 8; ++ni)
#pragma unroll
        for (int r = 0; r < 4; ++r)
            epit[(wm + lq * 4 + r) * 132 + ni * 16 + lr] = acc[ni][r];
    __syncthreads();
    for (int i = tid; i < 2048; i += 256) {
        int row = i >> 5, col = (i & 31) * 4;
        float4 v = *(const float4*)&epit[row * 132 + col];
        float4 old = *(const float4*)&h[(tokBase + row) * DM + col];
        old.x += v.x; old.y += v.y; old.z += v.z; old.w += v.w;
        *(float4*)&h[(tokBase + row) * DM + col] = old;
    }
}

// ---------------------------------------------------------------------------
__global__ __launch_bounds__(256) void k_final(float* __restrict__ h,
                                               const float* __restrict__ w,
                                               const float* __restrict__ bias,
                                               float* __restrict__ hg) {
    __shared__ float sbuf[DM];
    int t    = blockIdx.x * 16 + (threadIdx.x >> 4);
    int lane = threadIdx.x & 15;
    int b    = t >> 13;
    if (threadIdx.x < DM) sbuf[threadIdx.x] = 0.f;
    __syncthreads();
    float4* hp = (float4*)(h + (size_t)t * DM + lane * 8);
    float4 v0 = hp[0], v1 = hp[1];
    float s = v0.x + v0.y + v0.z + v0.w + v1.x + v1.y + v1.z + v1.w;
    float q = v0.x*v0.x + v0.y*v0.y + v0.z*v0.z + v0.w*v0.w +
              v1.x*v1.x + v1.y*v1.y + v1.z*v1.z + v1.w*v1.w;
#pragma unroll
    for (int off = 1; off < 16; off <<= 1) {
        s += __shfl_xor(s, off);
        q += __shfl_xor(q, off);
    }
    float mean = s * (1.f / DM);
    float var  = q * (1.f / DM) - mean * mean;
    float rstd = rsqrtf(var + 1e-5f);
    const float4* wp = (const float4*)(w + lane * 8);
    const float4* bp = (const float4*)(bias + lane * 8);
    float4 w0 = wp[0], w1 = wp[1], b0 = bp[0], b1 = bp[1];
    float4 o0, o1;
    o0.x = (v0.x - mean) * rstd * w0.x + b0.x;
    o0.y = (v0.y - mean) * rstd * w0.y + b0.y;
    o0.z = (v0.z - mean) * rstd * w0.z + b0.z;
    o0.w = (v0.w - mean) * rstd * w0.w + b0.w;
    o1.x = (v1.x - mean) * rstd * w1.x + b1.x;
    o1.y = (v1.y - mean) * rstd * w1.y + b1.y;
    o1.z = (v1.z - mean) * rstd * w1.z + b1.z;
    o1.w = (v1.w - mean) * rstd * w1.w + b1.w;
    hp[0] = o0; hp[1] = o1;
    int dbase = lane * 8;
    atomicAdd(&sbuf[dbase + 0], o0.x); atomicAdd(&sbuf[dbase + 1], o0.y);
    atomicAdd(&sbuf[dbase + 2], o0.z); atomicAdd(&sbuf[dbase + 3], o0.w);
    atomicAdd(&sbuf[dbase + 4], o1.x); atomicAdd(&sbuf[dbase + 5], o1.y);
    atomicAdd(&sbuf[dbase + 6], o1.z); atomicAdd(&sbuf[dbase + 7], o1.w);
    __syncthreads();
    if (threadIdx.x < DM)
        atomicAdd(&hg[b * DM + threadIdx.x], sbuf[threadIdx.x] * (1.f / Lz));
}

// ---------------------------------------------------------------------------
extern "C" void kernel_launch(void* const* d_in, const int* in_sizes, int n_in,
                              void* d_out, int out_size, void* d_ws, size_t ws_size,
                              hipStream_t stream) {
    const float* x       = (const float*)d_in[0];
    const float* proj_w  = (const float*)d_in[1];
    const float* proj_b  = (const float*)d_in[2];
    const float* ln_w    = (const float*)d_in[3];
    const float* ln_b    = (const float*)d_in[4];
    const float* in_w    = (const float*)d_in[5];
    const float* conv_w  = (const float*)d_in[6];
    const float* conv_b  = (const float*)d_in[7];
    const float* xproj_w = (const float*)d_in[8];
    const float* dt_w    = (const float*)d_in[9];
    const float* dt_b    = (const float*)d_in[10];
    const float* A_log   = (const float*)d_in[11];
    const float* Dp      = (const float*)d_in[12];
    const float* out_w   = (const float*)d_in[13];
    const float* lnout_w = (const float*)d_in[14];
    const float* lnout_b = (const float*)d_in[15];

    float* out = (float*)d_out;
    float* h   = out;                        // [BL][128] lives in d_out
    float* hg  = out + (size_t)BLz * DM;     // [B][128]

    // Workspace layout (~126 MiB)
    char* ws = (char*)d_ws;
    bf16_t* u_pre = (bf16_t*)(ws);                    // 32 MiB
    bf16_t* zs    = (bf16_t*)(ws + 33554432ULL);      // 32 MiB
    bf16_t* ybase = (bf16_t*)(ws + 67108864ULL);      // 32 MiB
    float*  dtc   = (float*) (ws + 100663296ULL);     // 6 MiB  (BL*24*4)
    float*  Q     = (float*) (ws + 106954752ULL);     // 16 MiB
    float*  sdtb  = (float*) (ws + 123731968ULL);     // 1 MiB
    bf16_t* inwb  = (bf16_t*)(ws + 124780544ULL);     // 512 KiB
    bf16_t* owb   = (bf16_t*)(ws + 125304832ULL);     // 256 KiB
    bf16_t* xwb   = (bf16_t*)(ws + 125566976ULL);     // 128 KiB

    k_zero_hg<<<4, 256, 0, stream>>>(hg);
    k_wconv<<<1024, 256, 0, stream>>>(in_w, out_w, xproj_w, inwb, owb, xwb);
    k_inproj<<<BLz / 2, 256, 0, stream>>>(x, proj_w, proj_b, h);

    for (int i = 0; i < DEPTHN; ++i) {
        k_lnin<<<BLz / 64, 256, 0, stream>>>(
            h, ln_w + i * DM, ln_b + i * DM,
            inwb + (size_t)i * 512 * DM, u_pre, zs);
        k_xp_scan1<<<BLz / CHT, 256, 0, stream>>>(
            u_pre, xwb + (size_t)i * 64 * DI,
            conv_w + i * DI * 4, conv_b + i * DI,
            dt_w + i * DI * DTR, dt_b + i * DI, A_log + i * DI * DS,
            Dp + i * DI, dtc, Q, sdtb, ybase);
        k_scan2<<<(Bz * DI * DS) / 256, 256, 0, stream>>>(
            Q, sdtb, A_log + i * DI * DS);
        k_corr_out<<<BLz / CHT, 256, 0, stream>>>(
            dtc, ybase, zs,
            dt_w + i * DI * DTR, dt_b + i * DI,
            A_log + i * DI * DS, Q,
            owb + (size_t)i * DM * DI, h);
    }

    k_final<<<BLz / 16, 256, 0, stream>>>(h, lnout_w, lnout_b, hg);
}

// Round 9
// 997.594 us; speedup vs baseline: 1.1304x; 1.0036x over previous
//
#include <hip/hip_runtime.h>
#include <hip/hip_bf16.h>
#include <math.h>

// Problem constants (MambaEncoder)
#define Bz     8
#define Lz     8192
#define DM     128      // d_model
#define DI     256      // d_inner
#define DS     16       // d_state
#define DTR    8        // dt_rank
#define NDBL   40       // DTR + 2*DS
#define DEPTHN 4
#define BLz    (Bz*Lz)  // 65536 tokens
#define CHT    64       // scan chunk length == M-tile
#define NCH    (Lz/CHT) // 128 chunks per sequence
#define PADI   264      // bf16 tile row stride
#define PADD   44       // f32 Db row stride

typedef unsigned short bf16_t;
typedef __attribute__((ext_vector_type(8))) __bf16 bf8;
typedef __attribute__((ext_vector_type(4))) float f4;
typedef __attribute__((ext_vector_type(8))) unsigned short us8;

__device__ __forceinline__ float bf2f(bf16_t u) {
    return __uint_as_float(((unsigned)u) << 16);
}
__device__ __forceinline__ bf16_t f2bf(float f) {
    unsigned u = __float_as_uint(f);
    u = u + 0x7FFFu + ((u >> 16) & 1u);   // round-to-nearest-even
    return (bf16_t)(u >> 16);
}
__device__ __forceinline__ float fast_rcp(float x) {
    return __builtin_amdgcn_rcpf(x);
}

// dA power tree: dA[s] = e1^(s+1), depth 4.
__device__ __forceinline__ void pow_tree(float e1, float dA[DS]) {
    float e2 = e1 * e1, e3 = e2 * e1, e4 = e2 * e2;
    float e8 = e4 * e4;
    dA[0] = e1;       dA[1] = e2;       dA[2] = e3;       dA[3] = e4;
    dA[4] = e4 * e1;  dA[5] = e4 * e2;  dA[6] = e4 * e3;  dA[7] = e8;
    dA[8] = e8 * e1;  dA[9] = e8 * e2;  dA[10] = e8 * e3; dA[11] = e8 * e4;
    dA[12] = e8 * dA[4]; dA[13] = e8 * dA[5]; dA[14] = e8 * dA[6];
    dA[15] = e8 * e8;
}

// ---------------------------------------------------------------------------
// Convert weights fp32 -> bf16 (xproj padded 40->64 rows) + zero hg.
// ---------------------------------------------------------------------------
__global__ __launch_bounds__(256) void k_wconv(const float* __restrict__ inw,
                                               const float* __restrict__ ow,
                                               const float* __restrict__ xw,
                                               bf16_t* __restrict__ inwb,
                                               bf16_t* __restrict__ owb,
                                               bf16_t* __restrict__ xwb,
                                               float* __restrict__ hg) {
    int i = blockIdx.x * 256 + threadIdx.x;
    if (i < Bz * DM) hg[i] = 0.f;
    if (i < DEPTHN * 512 * DM) inwb[i] = f2bf(inw[i]);
    if (i < DEPTHN * DM * DI)  owb[i]  = f2bf(ow[i]);
    if (i < DEPTHN * 64 * DI) {
        int layer = i >> 14, rk = i & 16383, r = rk >> 8, k = rk & 255;
        xwb[i] = (r < NDBL) ? f2bf(xw[((size_t)layer * NDBL + r) * DI + k]) : (bf16_t)0;
    }
}

// ---------------------------------------------------------------------------
__global__ __launch_bounds__(256) void k_inproj(const float* __restrict__ x,
                                                const float* __restrict__ pw,
                                                const float* __restrict__ pb,
                                                float* __restrict__ h) {
    int t = blockIdx.x * 2 + (threadIdx.x >> 7);
    int d = threadIdx.x & 127;
    int b = t >> 13, l = t & (Lz - 1);
    float acc = pb[d];
#pragma unroll
    for (int c = 0; c < 3; ++c)
        acc += x[(size_t)(b * 3 + c) * Lz + l] * pw[d * 3 + c];
    h[(size_t)t * DM + d] = acc;
}

// ---------------------------------------------------------------------------
// FUSED: LayerNorm (64 rows) -> in-proj GEMM [64x512] -> u_pre (raw) + zs
// (silu pre-applied). xn tile lives only in LDS. One block per 64 tokens.
// ---------------------------------------------------------------------------
__global__ __launch_bounds__(256) void k_lnin(const float* __restrict__ h,
                                              const float* __restrict__ lw,
                                              const float* __restrict__ lb,
                                              const bf16_t* __restrict__ inwb,
                                              bf16_t* __restrict__ u_pre,
                                              bf16_t* __restrict__ zs) {
    __shared__ bf16_t sm[64 * PADI];     // 33792 B; xs view (stride 136) first
    bf16_t* xs = sm;                      // 64 x 136 region
    int tid = threadIdx.x;
    int mBase = blockIdx.x * 64;

    // --- LayerNorm: 4 passes of 16 rows, 16 lanes/row ---
#pragma unroll
    for (int p = 0; p < 4; ++p) {
        int row = p * 16 + (tid >> 4);
        int lane = tid & 15;
        const float4* hp = (const float4*)(h + (size_t)(mBase + row) * DM + lane * 8);
        float4 v0 = hp[0], v1 = hp[1];
        float s = v0.x + v0.y + v0.z + v0.w + v1.x + v1.y + v1.z + v1.w;
        float q = v0.x*v0.x + v0.y*v0.y + v0.z*v0.z + v0.w*v0.w +
                  v1.x*v1.x + v1.y*v1.y + v1.z*v1.z + v1.w*v1.w;
#pragma unroll
        for (int off = 1; off < 16; off <<= 1) {
            s += __shfl_xor(s, off);
            q += __shfl_xor(q, off);
        }
        float mean = s * (1.f / DM);
        float var  = q * (1.f / DM) - mean * mean;
        float rstd = rsqrtf(var + 1e-5f);
        const float4* wp = (const float4*)(lw + lane * 8);
        const float4* bp = (const float4*)(lb + lane * 8);
        float4 w0 = wp[0], w1 = wp[1], b0 = bp[0], b1 = bp[1];
        ushort4 o0, o1;
        o0.x = f2bf((v0.x - mean) * rstd * w0.x + b0.x);
        o0.y = f2bf((v0.y - mean) * rstd * w0.y + b0.y);
        o0.z = f2bf((v0.z - mean) * rstd * w0.z + b0.z);
        o0.w = f2bf((v0.w - mean) * rstd * w0.w + b0.w);
        o1.x = f2bf((v1.x - mean) * rstd * w1.x + b1.x);
        o1.y = f2bf((v1.y - mean) * rstd * w1.y + b1.y);
        o1.z = f2bf((v1.z - mean) * rstd * w1.z + b1.z);
        o1.w = f2bf((v1.w - mean) * rstd * w1.w + b1.w);
        *(ushort4*)&xs[row * 136 + lane * 8]     = o0;
        *(ushort4*)&xs[row * 136 + lane * 8 + 4] = o1;
    }
    __syncthreads();

    // --- GEMM: [64 x 512] = xs[64 x 128] @ in_w^T; wave n-slice 128 ---
    int wave = tid >> 6, lane = tid & 63;
    int lr = lane & 15, lq = lane >> 4;
    int wn = wave * 128;
    f4 zf = {0.f, 0.f, 0.f, 0.f};
    f4 acc[4][8];
#pragma unroll
    for (int mi = 0; mi < 4; ++mi)
#pragma unroll
        for (int ni = 0; ni < 8; ++ni) acc[mi][ni] = zf;
    const bf16_t* Bp = inwb + (size_t)(wn + lr) * DM + lq * 8;
#pragma unroll
    for (int kk = 0; kk < DM; kk += 32) {
        bf8 af[4], bq[8];
#pragma unroll
        for (int mi = 0; mi < 4; ++mi)
            af[mi] = *(const bf8*)&xs[(mi * 16 + lr) * 136 + lq * 8 + kk];
#pragma unroll
        for (int ni = 0; ni < 8; ++ni)
            bq[ni] = *(const bf8*)(Bp + (size_t)ni * 16 * DM + kk);
#pragma unroll
        for (int mi = 0; mi < 4; ++mi)
#pragma unroll
            for (int ni = 0; ni < 8; ++ni)
                acc[mi][ni] = __builtin_amdgcn_mfma_f32_16x16x32_bf16(
                    af[mi], bq[ni], acc[mi][ni], 0, 0, 0);
    }
    __syncthreads();   // xs dead; sm reusable as 64x264 output tile

    // --- epilogue pass 1: u (cols 0..255, waves 0,1), raw bf16 ---
    if (wave < 2) {
#pragma unroll
        for (int mi = 0; mi < 4; ++mi)
#pragma unroll
            for (int ni = 0; ni < 8; ++ni)
#pragma unroll
                for (int r = 0; r < 4; ++r)
                    sm[(mi * 16 + lq * 4 + r) * PADI + wn + ni * 16 + lr] =
                        f2bf(acc[mi][ni][r]);
    }
    __syncthreads();
    for (int i = tid; i < 2048; i += 256) {
        int row = i >> 5, col = (i & 31) * 8;
        us8 v = *(const us8*)&sm[row * PADI + col];
        *(us8*)&u_pre[(size_t)(mBase + row) * DI + col] = v;
    }
    __syncthreads();
    // --- epilogue pass 2: zs = silu(z) (cols 256..511, waves 2,3) ---
    if (wave >= 2) {
#pragma unroll
        for (int mi = 0; mi < 4; ++mi)
#pragma unroll
            for (int ni = 0; ni < 8; ++ni)
#pragma unroll
                for (int r = 0; r < 4; ++r) {
                    float v = acc[mi][ni][r];
                    float sil = v * fast_rcp(1.f + __expf(-v));
                    sm[(mi * 16 + lq * 4 + r) * PADI + (wn - 256) + ni * 16 + lr] =
                        f2bf(sil);
                }
    }
    __syncthreads();
    for (int i = tid; i < 2048; i += 256) {
        int row = i >> 5, col = (i & 31) * 8;
        us8 v = *(const us8*)&sm[row * PADI + col];
        *(us8*)&zs[(size_t)(mBase + row) * DI + col] = v;
    }
}

// ---------------------------------------------------------------------------
// FUSED: coalesced u_pre staging -> in-LDS conv+SiLU -> xproj GEMM ->
// scan1 with local-y: ybase = C·h_local + u·Dp (bf16), Q, sdt, dtc (dt+C).
// ---------------------------------------------------------------------------
__global__ __launch_bounds__(256, 3) void k_xp_scan1(
        const bf16_t* __restrict__ u_pre, const bf16_t* __restrict__ xwb,
        const float* __restrict__ cw, const float* __restrict__ cb,
        const float* __restrict__ dtw, const float* __restrict__ dtb,
        const float* __restrict__ Alog, const float* __restrict__ Dpv,
        float* __restrict__ dtc, float* __restrict__ Q,
        float* __restrict__ sdtb, bf16_t* __restrict__ ybase) {
    __shared__ bf16_t As[CHT * PADI];  // 33792 B
    __shared__ float  Db[CHT * PADD];  // 11264 B
    int tid = threadIdx.x;
    size_t tokBase = (size_t)blockIdx.x * CHT;
    int b  = (int)(tokBase >> 13);
    int p0 = (int)(tokBase & (Lz - 1));
    int c  = p0 >> 6;

    // halo (3 tokens before chunk; p0 is 0 or >=64)
    int d = tid;
    float hx3 = 0.f, hx2 = 0.f, hx1 = 0.f;
    if (p0 != 0) {
        size_t hb = tokBase * DI + d;
        hx3 = bf2f(u_pre[hb - 3 * DI]);
        hx2 = bf2f(u_pre[hb - 2 * DI]);
        hx1 = bf2f(u_pre[hb - 1 * DI]);
    }
    // coalesced staging of raw u_pre tile
    for (int i = tid; i < 2048; i += 256) {
        int row = i >> 5, col = (i & 31) * 8;
        us8 v = *(const us8*)&u_pre[(tokBase + row) * DI + col];
        *(us8*)&As[row * PADI + col] = v;
    }
    __syncthreads();

    // --- conv(k=4)+SiLU in place (column-private) ---
    {
        float w0 = cw[d*4+0], w1 = cw[d*4+1], w2 = cw[d*4+2], w3 = cw[d*4+3];
        float bb = cb[d];
        float x3 = hx3, x2 = hx2, x1 = hx1;
#pragma unroll 8
        for (int t = 0; t < CHT; ++t) {
            float x0 = bf2f(As[t * PADI + d]);
            float conv = bb + w0*x3 + w1*x2 + w2*x1 + w3*x0;
            float sil = conv * fast_rcp(1.f + __expf(-conv));
            As[t * PADI + d] = f2bf(sil);
            x3 = x2; x2 = x1; x1 = x0;
        }
    }
    __syncthreads();

    // --- xproj GEMM: Db[64 x 40] = u @ xw^T (N padded to 64) ---
    {
        int wave = tid >> 6, lane = tid & 63;
        int lr = lane & 15, lq = lane >> 4;
        int wm = wave * 16;
        f4 zf = {0.f, 0.f, 0.f, 0.f};
        f4 acc[4];
#pragma unroll
        for (int ni = 0; ni < 4; ++ni) acc[ni] = zf;
        const bf16_t* Bp = xwb + (size_t)lr * DI + lq * 8;
#pragma unroll
        for (int kk = 0; kk < DI; kk += 32) {
            bf8 af = *(const bf8*)&As[(wm + lr) * PADI + lq * 8 + kk];
            bf8 bq[4];
#pragma unroll
            for (int ni = 0; ni < 4; ++ni)
                bq[ni] = *(const bf8*)(Bp + (size_t)ni * 16 * DI + kk);
#pragma unroll
            for (int ni = 0; ni < 4; ++ni)
                acc[ni] = __builtin_amdgcn_mfma_f32_16x16x32_bf16(
                    af, bq[ni], acc[ni], 0, 0, 0);
        }
#pragma unroll
        for (int ni = 0; ni < 4; ++ni)
#pragma unroll
            for (int r = 0; r < 4; ++r) {
                int col = ni * 16 + lr;
                if (col < NDBL)
                    Db[(wm + lq * 4 + r) * PADD + col] = acc[ni][r];
            }
    }
    __syncthreads();
    // dtc (dt cols 0..7 + C cols 24..39 -> 24 cols) to global
    for (int i = tid; i < CHT * 24; i += 256) {
        int row = i / 24, cc = i - row * 24;
        dtc[(tokBase + row) * 24 + cc] = Db[row * PADD + (cc < 8 ? cc : cc + 16)];
    }

    // --- scan1 + local y ---
    {
        float w[DTR];
#pragma unroll
        for (int r = 0; r < DTR; ++r) w[r] = dtw[d * DTR + r];
        float bb = dtb[d];
        float dp = Dpv[d];
        float a[DS], q[DS];
        const float4* ap = (const float4*)(Alog + d * DS);
#pragma unroll
        for (int s4 = 0; s4 < 4; ++s4) {
            float4 av = ap[s4];
            a[s4*4+0] = -__expf(av.x); a[s4*4+1] = -__expf(av.y);
            a[s4*4+2] = -__expf(av.z); a[s4*4+3] = -__expf(av.w);
        }
#pragma unroll
        for (int s = 0; s < DS; ++s) q[s] = 0.f;
        float a0 = a[0];
        bool fast = true;
#pragma unroll
        for (int s = 1; s < DS; ++s) {
            float ref = a0 * (float)(s + 1);
            fast = fast && (fabsf(a[s] - ref) <= 1e-5f * fabsf(ref) + 1e-7f);
        }
        float sdt = 0.f;
        bf16_t* yp = ybase + tokBase * DI + d;
        if (fast) {
#pragma unroll 4
            for (int t = 0; t < CHT; ++t) {
                float4 r0 = *(const float4*)&Db[t * PADD + 0];
                float4 r1 = *(const float4*)&Db[t * PADD + 4];
                float xv = bb + r0.x*w[0] + r0.y*w[1] + r0.z*w[2] + r0.w*w[3]
                              + r1.x*w[4] + r1.y*w[5] + r1.z*w[6] + r1.w*w[7];
                float dtv = (xv > 20.f) ? xv : __logf(1.f + __expf(xv));
                sdt += dtv;
                float uv = bf2f(As[t * PADI + d]);
                float dtu = dtv * uv;
                float e1 = __expf(dtv * a0);
                float dA[DS];
                pow_tree(e1, dA);
                float bv[DS], cv[DS];
                *(float4*)&bv[0]  = *(const float4*)&Db[t * PADD + 8];
                *(float4*)&bv[4]  = *(const float4*)&Db[t * PADD + 12];
                *(float4*)&bv[8]  = *(const float4*)&Db[t * PADD + 16];
                *(float4*)&bv[12] = *(const float4*)&Db[t * PADD + 20];
                *(float4*)&cv[0]  = *(const float4*)&Db[t * PADD + 24];
                *(float4*)&cv[4]  = *(const float4*)&Db[t * PADD + 28];
                *(float4*)&cv[8]  = *(const float4*)&Db[t * PADD + 32];
                *(float4*)&cv[12] = *(const float4*)&Db[t * PADD + 36];
                float y0 = 0.f, y1 = 0.f, y2 = 0.f, y3 = 0.f;
#pragma unroll
                for (int s = 0; s < DS; s += 4) {
                    q[s]   = q[s]   * dA[s]   + dtu * bv[s];
                    q[s+1] = q[s+1] * dA[s+1] + dtu * bv[s+1];
                    q[s+2] = q[s+2] * dA[s+2] + dtu * bv[s+2];
                    q[s+3] = q[s+3] * dA[s+3] + dtu * bv[s+3];
                    y0 += q[s]   * cv[s];
                    y1 += q[s+1] * cv[s+1];
                    y2 += q[s+2] * cv[s+2];
                    y3 += q[s+3] * cv[s+3];
                }
                float y = (y0 + y1) + (y2 + y3);
                yp[(size_t)t * DI] = f2bf(y + uv * dp);
            }
        } else {
            for (int t = 0; t < CHT; ++t) {
                float4 r0 = *(const float4*)&Db[t * PADD + 0];
                float4 r1 = *(const float4*)&Db[t * PADD + 4];
                float xv = bb + r0.x*w[0] + r0.y*w[1] + r0.z*w[2] + r0.w*w[3]
                              + r1.x*w[4] + r1.y*w[5] + r1.z*w[6] + r1.w*w[7];
                float dtv = (xv > 20.f) ? xv : __logf(1.f + __expf(xv));
                sdt += dtv;
                float uv = bf2f(As[t * PADI + d]);
                float dtu = dtv * uv;
                float bv[DS], cv[DS];
                *(float4*)&bv[0]  = *(const float4*)&Db[t * PADD + 8];
                *(float4*)&bv[4]  = *(const float4*)&Db[t * PADD + 12];
                *(float4*)&bv[8]  = *(const float4*)&Db[t * PADD + 16];
                *(float4*)&bv[12] = *(const float4*)&Db[t * PADD + 20];
                *(float4*)&cv[0]  = *(const float4*)&Db[t * PADD + 24];
                *(float4*)&cv[4]  = *(const float4*)&Db[t * PADD + 28];
                *(float4*)&cv[8]  = *(const float4*)&Db[t * PADD + 32];
                *(float4*)&cv[12] = *(const float4*)&Db[t * PADD + 36];
                float y = 0.f;
#pragma unroll
                for (int s = 0; s < DS; ++s) {
                    float dA = __expf(dtv * a[s]);
                    q[s] = q[s] * dA + dtu * bv[s];
                    y += q[s] * cv[s];
                }
                yp[(size_t)t * DI] = f2bf(y + uv * dp);
            }
        }
        size_t o = ((size_t)(b * NCH + c) * DI + d) * DS;
#pragma unroll
        for (int s = 0; s < DS; s += 4)
            *(float4*)&Q[o + s] = make_float4(q[s], q[s+1], q[s+2], q[s+3]);
        sdtb[(size_t)(b * NCH + c) * DI + d] = sdt;
    }
}

// ---------------------------------------------------------------------------
// Phase 2: decay from sdt (exact: prod exp(dtv*a) == exp(a*sum dtv)).
// Q[c] overwritten in place with chunk entry state. 16-deep prefetch.
// ---------------------------------------------------------------------------
__global__ __launch_bounds__(256) void k_scan2(float* __restrict__ Q,
                                               const float* __restrict__ sdtb,
                                               const float* __restrict__ Alog) {
    int gid = blockIdx.x * 256 + threadIdx.x;   // Bz*DI*DS threads
    int b = gid >> 12, r = gid & 4095;          // r = d*16 + s
    int d = r >> 4, s = r & 15;
    float a = -__expf(Alog[d * DS + s]);
    const size_t stride = (size_t)DI * DS;
    size_t base = (size_t)b * NCH * stride + r;
    const float* sp = sdtb + (size_t)b * NCH * DI + d;
    float hh = 0.f;
    for (int g = 0; g < NCH / 16; ++g) {
        float qq[16], ee[16];
#pragma unroll
        for (int j = 0; j < 16; ++j)
            qq[j] = Q[base + (size_t)(g * 16 + j) * stride];
#pragma unroll
        for (int j = 0; j < 16; ++j)
            ee[j] = __expf(a * sp[(size_t)(g * 16 + j) * DI]);
#pragma unroll
        for (int j = 0; j < 16; ++j) {
            size_t o = base + (size_t)(g * 16 + j) * stride;
            Q[o] = hh;
            hh = ee[j] * hh + qq[j];
        }
    }
}

// ---------------------------------------------------------------------------
// FUSED: correction + gate -> y tile -> out-GEMM h += y @ out_w^T.
// y_t = ybase_t + sum_s C_t[s]*H0[s]*exp(a[s]*cdt_t); out = y * zs.
// ---------------------------------------------------------------------------
__global__ __launch_bounds__(256, 4) void k_corr_out(
        const float* __restrict__ dtc, const bf16_t* __restrict__ ybase,
        const bf16_t* __restrict__ zs,
        const float* __restrict__ dtw, const float* __restrict__ dtb,
        const float* __restrict__ Alog, const float* __restrict__ H0,
        const bf16_t* __restrict__ owb, float* __restrict__ h) {
    __shared__ float epit[CHT * 132];  // 33792 B; aliased as bf16 y tile
    __shared__ float Dt8[CHT * 8];     // 2048 B
    __shared__ float Cs[CHT * DS];     // 4096 B
    bf16_t* yt = (bf16_t*)epit;

    int tid = threadIdx.x;
    size_t tokBase = (size_t)blockIdx.x * CHT;
    int b  = (int)(tokBase >> 13);
    int p0 = (int)(tokBase & (Lz - 1));
    int c  = p0 >> 6;

    for (int i = tid; i < CHT * 24; i += 256) {
        float v = dtc[tokBase * 24 + i];
        int t = i / 24, col = i - t * 24;
        if (col < 8) Dt8[t * 8 + col] = v;
        else         Cs[t * DS + (col - 8)] = v;
    }
    __syncthreads();

    // --- correction + gating (thread = d) ---
    {
        int d = tid;
        float w[DTR];
#pragma unroll
        for (int r = 0; r < DTR; ++r) w[r] = dtw[d * DTR + r];
        float bb = dtb[d];
        float a[DS], gh[DS];
        const float4* ap = (const float4*)(Alog + d * DS);
#pragma unroll
        for (int s4 = 0; s4 < 4; ++s4) {
            float4 av = ap[s4];
            a[s4*4+0] = -__expf(av.x); a[s4*4+1] = -__expf(av.y);
            a[s4*4+2] = -__expf(av.z); a[s4*4+3] = -__expf(av.w);
        }
        size_t ho = ((size_t)(b * NCH + c) * DI + d) * DS;
#pragma unroll
        for (int s = 0; s < DS; s += 4) {
            float4 hv = *(const float4*)&H0[ho + s];
            gh[s] = hv.x; gh[s+1] = hv.y; gh[s+2] = hv.z; gh[s+3] = hv.w;
        }
        float a0 = a[0];
        bool fast = true;
#pragma unroll
        for (int s = 1; s < DS; ++s) {
            float ref = a0 * (float)(s + 1);
            fast = fast && (fabsf(a[s] - ref) <= 1e-5f * fabsf(ref) + 1e-7f);
        }
        const bf16_t* yp = ybase + tokBase * DI + d;
        const bf16_t* zp = zs + tokBase * DI + d;
        float cdt = 0.f;
        float yc[4], zc[4];
#pragma unroll
        for (int j = 0; j < 4; ++j) {
            yc[j] = bf2f(yp[(size_t)j * DI]);
            zc[j] = bf2f(zp[(size_t)j * DI]);
        }
        for (int g = 0; g < CHT / 4; ++g) {
            float yn[4] = {0,0,0,0}, zn[4] = {0,0,0,0};
            if (g + 1 < CHT / 4) {
#pragma unroll
                for (int j = 0; j < 4; ++j) {
                    yn[j] = bf2f(yp[(size_t)((g + 1) * 4 + j) * DI]);
                    zn[j] = bf2f(zp[(size_t)((g + 1) * 4 + j) * DI]);
                }
            }
#pragma unroll
            for (int j = 0; j < 4; ++j) {
                int t = g * 4 + j;
                float4 r0 = *(const float4*)&Dt8[t * 8];
                float4 r1 = *(const float4*)&Dt8[t * 8 + 4];
                float xv = bb + r0.x*w[0] + r0.y*w[1] + r0.z*w[2] + r0.w*w[3]
                              + r1.x*w[4] + r1.y*w[5] + r1.z*w[6] + r1.w*w[7];
                float dtv = (xv > 20.f) ? xv : __logf(1.f + __expf(xv));
                cdt += dtv;
                float cv[DS];
                *(float4*)&cv[0]  = *(const float4*)&Cs[t * DS + 0];
                *(float4*)&cv[4]  = *(const float4*)&Cs[t * DS + 4];
                *(float4*)&cv[8]  = *(const float4*)&Cs[t * DS + 8];
                *(float4*)&cv[12] = *(const float4*)&Cs[t * DS + 12];
                float corr0 = 0.f, corr1 = 0.f, corr2 = 0.f, corr3 = 0.f;
                if (fast) {
                    float e1 = __expf(a0 * cdt);
                    float dA[DS];
                    pow_tree(e1, dA);
#pragma unroll
                    for (int s = 0; s < DS; s += 4) {
                        corr0 += cv[s]   * (gh[s]   * dA[s]);
                        corr1 += cv[s+1] * (gh[s+1] * dA[s+1]);
                        corr2 += cv[s+2] * (gh[s+2] * dA[s+2]);
                        corr3 += cv[s+3] * (gh[s+3] * dA[s+3]);
                    }
                } else {
#pragma unroll
                    for (int s = 0; s < DS; ++s)
                        corr0 += cv[s] * (gh[s] * __expf(a[s] * cdt));
                }
                float y = yc[j] + ((corr0 + corr1) + (corr2 + corr3));
                yt[t * PADI + d] = f2bf(y * zc[j]);
            }
#pragma unroll
            for (int j = 0; j < 4; ++j) { yc[j] = yn[j]; zc[j] = zn[j]; }
        }
    }
    __syncthreads();

    // --- out-GEMM: h[64 x 128] += y[64 x 256] @ out_w^T ---
    int wave = tid >> 6, lane = tid & 63;
    int lr = lane & 15, lq = lane >> 4;
    int wm = wave * 16;
    f4 zf = {0.f, 0.f, 0.f, 0.f};
    f4 acc[8];
#pragma unroll
    for (int ni = 0; ni < 8; ++ni) acc[ni] = zf;
    const bf16_t* Bp = owb + (size_t)lr * DI + lq * 8;
#pragma unroll
    for (int kk = 0; kk < DI; kk += 32) {
        bf8 af = *(const bf8*)&yt[(wm + lr) * PADI + lq * 8 + kk];
        bf8 bq[8];
#pragma unroll
        for (int ni = 0; ni < 8; ++ni)
            bq[ni] = *(const bf8*)(Bp + (size_t)ni * 16 * DI + kk);
#pragma unroll
        for (int ni = 0; ni < 8; ++ni)
            acc[ni] = __builtin_amdgcn_mfma_f32_16x16x32_bf16(
                af, bq[ni], acc[ni], 0, 0, 0);
    }
    __syncthreads();   // yt reads done; epit may be overwritten
#pragma unroll
    for (int ni = 0; ni < 8; ++ni)
#pragma unroll
        for (int r = 0; r < 4; ++r)
            epit[(wm + lq * 4 + r) * 132 + ni * 16 + lr] = acc[ni][r];
    __syncthreads();
    for (int i = tid; i < 2048; i += 256) {
        int row = i >> 5, col = (i & 31) * 4;
        float4 v = *(const float4*)&epit[row * 132 + col];
        float4 old = *(const float4*)&h[(tokBase + row) * DM + col];
        old.x += v.x; old.y += v.y; old.z += v.z; old.w += v.w;
        *(float4*)&h[(tokBase + row) * DM + col] = old;
    }
}

// ---------------------------------------------------------------------------
__global__ __launch_bounds__(256) void k_final(float* __restrict__ h,
                                               const float* __restrict__ w,
                                               const float* __restrict__ bias,
                                               float* __restrict__ hg) {
    __shared__ float sbuf[DM];
    int t    = blockIdx.x * 16 + (threadIdx.x >> 4);
    int lane = threadIdx.x & 15;
    int b    = t >> 13;
    if (threadIdx.x < DM) sbuf[threadIdx.x] = 0.f;
    __syncthreads();
    float4* hp = (float4*)(h + (size_t)t * DM + lane * 8);
    float4 v0 = hp[0], v1 = hp[1];
    float s = v0.x + v0.y + v0.z + v0.w + v1.x + v1.y + v1.z + v1.w;
    float q = v0.x*v0.x + v0.y*v0.y + v0.z*v0.z + v0.w*v0.w +
              v1.x*v1.x + v1.y*v1.y + v1.z*v1.z + v1.w*v1.w;
#pragma unroll
    for (int off = 1; off < 16; off <<= 1) {
        s += __shfl_xor(s, off);
        q += __shfl_xor(q, off);
    }
    float mean = s * (1.f / DM);
    float var  = q * (1.f / DM) - mean * mean;
    float rstd = rsqrtf(var + 1e-5f);
    const float4* wp = (const float4*)(w + lane * 8);
    const float4* bp = (const float4*)(bias + lane * 8);
    float4 w0 = wp[0], w1 = wp[1], b0 = bp[0], b1 = bp[1];
    float4 o0, o1;
    o0.x = (v0.x - mean) * rstd * w0.x + b0.x;
    o0.y = (v0.y - mean) * rstd * w0.y + b0.y;
    o0.z = (v0.z - mean) * rstd * w0.z + b0.z;
    o0.w = (v0.w - mean) * rstd * w0.w + b0.w;
    o1.x = (v1.x - mean) * rstd * w1.x + b1.x;
    o1.y = (v1.y - mean) * rstd * w1.y + b1.y;
    o1.z = (v1.z - mean) * rstd * w1.z + b1.z;
    o1.w = (v1.w - mean) * rstd * w1.w + b1.w;
    hp[0] = o0; hp[1] = o1;
    int dbase = lane * 8;
    atomicAdd(&sbuf[dbase + 0], o0.x); atomicAdd(&sbuf[dbase + 1], o0.y);
    atomicAdd(&sbuf[dbase + 2], o0.z); atomicAdd(&sbuf[dbase + 3], o0.w);
    atomicAdd(&sbuf[dbase + 4], o1.x); atomicAdd(&sbuf[dbase + 5], o1.y);
    atomicAdd(&sbuf[dbase + 6], o1.z); atomicAdd(&sbuf[dbase + 7], o1.w);
    __syncthreads();
    if (threadIdx.x < DM)
        atomicAdd(&hg[b * DM + threadIdx.x], sbuf[threadIdx.x] * (1.f / Lz));
}

// ---------------------------------------------------------------------------
extern "C" void kernel_launch(void* const* d_in, const int* in_sizes, int n_in,
                              void* d_out, int out_size, void* d_ws, size_t ws_size,
                              hipStream_t stream) {
    const float* x       = (const float*)d_in[0];
    const float* proj_w  = (const float*)d_in[1];
    const float* proj_b  = (const float*)d_in[2];
    const float* ln_w    = (const float*)d_in[3];
    const float* ln_b    = (const float*)d_in[4];
    const float* in_w    = (const float*)d_in[5];
    const float* conv_w  = (const float*)d_in[6];
    const float* conv_b  = (const float*)d_in[7];
    const float* xproj_w = (const float*)d_in[8];
    const float* dt_w    = (const float*)d_in[9];
    const float* dt_b    = (const float*)d_in[10];
    const float* A_log   = (const float*)d_in[11];
    const float* Dp      = (const float*)d_in[12];
    const float* out_w   = (const float*)d_in[13];
    const float* lnout_w = (const float*)d_in[14];
    const float* lnout_b = (const float*)d_in[15];

    float* out = (float*)d_out;
    float* h   = out;                        // [BL][128] lives in d_out
    float* hg  = out + (size_t)BLz * DM;     // [B][128]

    // Workspace layout (~108 MiB) — identical to the verified round-7 layout.
    char* ws = (char*)d_ws;
    bf16_t* u_pre = (bf16_t*)(ws);                    // 32 MiB
    bf16_t* zs    = (bf16_t*)(ws + 33554432ULL);      // 32 MiB
    bf16_t* ybase = (bf16_t*)(ws + 67108864ULL);      // 32 MiB
    float*  dtc   = (float*) (ws + 100663296ULL);     // 6 MiB  (BL*24*4)
    float*  Q     = (float*) (ws + 106954752ULL);     // 16 MiB
    float*  sdtb  = (float*) (ws + 123731968ULL);     // 1 MiB
    bf16_t* inwb  = (bf16_t*)(ws + 124780544ULL);     // 512 KiB
    bf16_t* owb   = (bf16_t*)(ws + 125304832ULL);     // 256 KiB
    bf16_t* xwb   = (bf16_t*)(ws + 125566976ULL);     // 128 KiB

    k_wconv<<<1024, 256, 0, stream>>>(in_w, out_w, xproj_w, inwb, owb, xwb, hg);
    k_inproj<<<BLz / 2, 256, 0, stream>>>(x, proj_w, proj_b, h);

    for (int i = 0; i < DEPTHN; ++i) {
        k_lnin<<<BLz / 64, 256, 0, stream>>>(
            h, ln_w + i * DM, ln_b + i * DM,
            inwb + (size_t)i * 512 * DM, u_pre, zs);
        k_xp_scan1<<<BLz / CHT, 256, 0, stream>>>(
            u_pre, xwb + (size_t)i * 64 * DI,
            conv_w + i * DI * 4, conv_b + i * DI,
            dt_w + i * DI * DTR, dt_b + i * DI, A_log + i * DI * DS,
            Dp + i * DI, dtc, Q, sdtb, ybase);
        k_scan2<<<(Bz * DI * DS) / 256, 256, 0, stream>>>(
            Q, sdtb, A_log + i * DI * DS);
        k_corr_out<<<BLz / CHT, 256, 0, stream>>>(
            dtc, ybase, zs,
            dt_w + i * DI * DTR, dt_b + i * DI,
            A_log + i * DI * DS, Q,
            owb + (size_t)i * DM * DI, h);
    }

    k_final<<<BLz / 16, 256, 0, stream>>>(h, lnout_w, lnout_b, hg);
}